// Round 17
// baseline (712.169 us; speedup 1.0000x reference)
//
#include <hip/hip_runtime.h>
#include <cfloat>

#define NROWS 131072
#define EDIM 256
#define NE 1024
#define DELTA 2.0e-4f

#define BM 128
#define BN 128
#define BK 32

typedef unsigned short u16;
typedef __attribute__((ext_vector_type(8))) short bf16x8;
typedef __attribute__((ext_vector_type(4))) float f32x4;

// ---- ws layout (bytes) ----
#define WS_Z2    0u
#define WS_E2    524288u
#define WS_PART  528384u        // 2560 doubles (2048 refine + 512 fallback)
#define WS_CNT   548864u
#define WS_LIST  549120u
#define WS_CI1   1073408u
#define WS_CI2   1597696u
#define WS_FLG   2121984u
#define WS_BP    2646272u
#define WS_END   4219136u

// ---------- numpy pairwise sum-of-squares (256 elems), serial form ----------
__device__ __forceinline__ float np_sumsq256(const float* __restrict__ row) {
    float s[2];
#pragma unroll
    for (int h = 0; h < 2; ++h) {
        const float* a = row + h * 128;
        float r[8];
#pragma unroll
        for (int j = 0; j < 8; ++j) r[j] = __fmul_rn(a[j], a[j]);
        for (int i = 8; i < 128; i += 8) {
#pragma unroll
            for (int j = 0; j < 8; ++j)
                r[j] = __fadd_rn(r[j], __fmul_rn(a[i + j], a[i + j]));
        }
        s[h] = __fadd_rn(__fadd_rn(__fadd_rn(r[0], r[1]), __fadd_rn(r[2], r[3])),
                         __fadd_rn(__fadd_rn(r[4], r[5]), __fadd_rn(r[6], r[7])));
    }
    return __fadd_rn(s[0], s[1]);
}

__device__ __forceinline__ u16 bf16_rn(float x) {
    unsigned u = __float_as_uint(x);
    return (u16)((u + 0x7fffu + ((u >> 16) & 1u)) >> 16);
}

// ---------- fused, COALESCED: z2 (numpy-pairwise via shfl tree) + z->zhi/zlo ----------
__global__ __launch_bounds__(256)
void rownorm_split_kernel(const float* __restrict__ z, float* __restrict__ z2out,
                          u16* __restrict__ zhi, u16* __restrict__ zlo) {
    __shared__ float zl[16 * 256];   // 16 KiB
    const int tid = threadIdx.x;
    const size_t base4 = (size_t)blockIdx.x * 1024;   // float4 index of block base

    {
        const float4* src = reinterpret_cast<const float4*>(z) + base4;
        float4* dst = reinterpret_cast<float4*>(zl);
#pragma unroll
        for (int i = 0; i < 4; ++i) dst[tid + 256 * i] = src[tid + 256 * i];
    }
    __syncthreads();

    {
        const int row = tid >> 4;
        const int j16 = tid & 15;
        const int h = j16 >> 3, j = j16 & 7;
        const float* a = &zl[row * 256 + h * 128];
        float r = __fmul_rn(a[j], a[j]);
#pragma unroll
        for (int i = 8; i < 128; i += 8)
            r = __fadd_rn(r, __fmul_rn(a[i + j], a[i + j]));
        r = __fadd_rn(r, __shfl_xor(r, 1));
        r = __fadd_rn(r, __shfl_xor(r, 2));
        r = __fadd_rn(r, __shfl_xor(r, 4));   // = s[h]
        r = __fadd_rn(r, __shfl_xor(r, 8));   // = s[0]+s[1]
        if (j16 == 0) z2out[blockIdx.x * 16 + row] = r;
    }

    {
        ushort4* ph = reinterpret_cast<ushort4*>(zhi) + base4;
        ushort4* pl = reinterpret_cast<ushort4*>(zlo) + base4;
        const float4* sp = reinterpret_cast<const float4*>(zl);
#pragma unroll
        for (int i = 0; i < 4; ++i) {
            const int q = tid + 256 * i;
            float4 v = sp[q];
            float xs[4] = {v.x, v.y, v.z, v.w};
            u16 hh[4], lo[4];
#pragma unroll
            for (int c = 0; c < 4; ++c) {
                u16 hv = bf16_rn(xs[c]);
                float hf = __uint_as_float(((unsigned)hv) << 16);
                hh[c] = hv;
                lo[c] = bf16_rn(__fsub_rn(xs[c], hf));
            }
            ph[q] = make_ushort4(hh[0], hh[1], hh[2], hh[3]);
            pl[q] = make_ushort4(lo[0], lo[1], lo[2], lo[3]);
        }
    }
}

__global__ __launch_bounds__(256)
void rownorm_kernel(const float* __restrict__ x, float* __restrict__ out, int nrows) {
    int row = blockIdx.x * blockDim.x + threadIdx.x;
    if (row < nrows) out[row] = np_sumsq256(x + (size_t)row * EDIM);
}

// B' layout: [e_hi | e_lo], stride 512 per code row
__global__ __launch_bounds__(256)
void build_b_kernel(const float* __restrict__ e, u16* __restrict__ Bp) {
    int idx = blockIdx.x * 256 + threadIdx.x;
    int row = idx >> 8, k = idx & 255;
    float x = e[idx];
    u16 hh = bf16_rn(x);
    float hf = __uint_as_float(((unsigned)hh) << 16);
    u16 lo = bf16_rn(__fsub_rn(x, hf));
    Bp[row * 512 + k] = hh;
    Bp[row * 512 + 256 + k] = lo;
}

__device__ __forceinline__ void gload_lds16(const void* g, void* lds) {
    __builtin_amdgcn_global_load_lds((const __attribute__((address_space(1))) void*)g,
                                     (__attribute__((address_space(3))) void*)lds,
                                     16, 0, 0);
}

#define LEXLT(va, ia, vb, ib) ((va) < (vb) || ((va) == (vb) && (ia) < (ib)))

#define MERGE5(a1, ai1, a2, ai2, a3, b1, bi1, b2, bi2, b3)                    \
    {                                                                         \
        float n1v, n2v, n3v; int n1i, n2i;                                    \
        if (LEXLT(a1, ai1, b1, bi1)) {                                        \
            n1v = a1; n1i = ai1;                                              \
            if (LEXLT(a2, ai2, b1, bi1)) { n2v = a2; n2i = ai2; n3v = fminf(a3, b1); } \
            else                          { n2v = b1; n2i = bi1; n3v = fminf(a2, b2); } \
        } else {                                                              \
            n1v = b1; n1i = bi1;                                              \
            if (LEXLT(b2, bi2, a1, ai1)) { n2v = b2; n2i = bi2; n3v = fminf(b3, a1); } \
            else                          { n2v = a1; n2i = ai1; n3v = fminf(b2, a2); } \
        }                                                                     \
        a1 = n1v; ai1 = n1i; a2 = n2v; ai2 = n2i; a3 = n3v;                   \
    }

#define WAITVM(N) asm volatile("s_waitcnt vmcnt(" #N ")" ::: "memory")
#define RBAR()    asm volatile("s_barrier" ::: "memory")

// ---------- K2: bf16 MFMA, D[code][z-row], tile 128x256, fr8 x fc4,
//            32-col chunks, double-buffered, counted-vmcnt pipeline ----------
// 256 thr / 4 waves (wrg 0..1 z-groups x wcg 0..1 code-groups).
// A0 = zhi chunk, A1 = zlo chunk (fixed roles); B alternates by j.
// Per (nc, j): 3 steps {zhi x ehi, zhi x elo, zlo x ehi}; stage 2 steps ahead.
// __launch_bounds__(256,2): 2 waves/SIMD -> VGPR cap 256 (needs ~215).
__global__ __launch_bounds__(256, 2)
void vq_mfma_kernel(const u16* __restrict__ zhi, const u16* __restrict__ zlo,
                    const u16* __restrict__ Bp, const float* __restrict__ e2f,
                    int* __restrict__ ci1, int* __restrict__ ci2, int* __restrict__ cflag) {
    __shared__ __align__(16) u16  At[2][128 * 32];  // 2 x 8 KiB (z col-chunk)
    __shared__ __align__(16) u16  Bt[2][256 * 32];  // 2 x 16 KiB (codes col-chunk)
    __shared__ float e2s[1024];                     // 4 KiB
    __shared__ float mrg[128 * 2 * 4];              // 4 KiB [row][wcg][v1,v2,v3,pk]

    const int tid = threadIdx.x;
    const int m0  = blockIdx.x * 128;
    const int l   = tid & 63;
    const int wid = tid >> 6;
    const int wrg = wid >> 1;       // 0..1 -> z-rows wrg*64
    const int wcg = wid & 1;        // 0..1 -> codes wcg*128 (within 256-chunk)
    const int lr  = l & 15;
    const int lg  = l >> 4;         // 0..3
    const int key = lr & 3;         // 4 chunks of 16B per 32-col row

#pragma unroll
    for (int i = 0; i < 4; ++i) e2s[tid + 256 * i] = e2f[tid + 256 * i];

    // staging map: chunk c = s*256+tid; row = s*64 + (tid>>2); phys = tid&3
    const int rsub4 = tid >> 2;                  // 0..63
    const int l4    = (tid & 3) ^ (rsub4 & 3);   // logical 16B chunk at this slot

#define SAT(BUF, SRC, COLC)                                                   \
    {                                                                         \
        _Pragma("unroll")                                                     \
        for (int s = 0; s < 2; ++s)                                           \
            gload_lds16((SRC) + (size_t)(m0 + s * 64 + rsub4) * 256 + (COLC) + l4 * 8, \
                        At[BUF] + (size_t)(s * 256 + tid) * 8);               \
    }
#define SBT(BUF, NB, OFF)                                                     \
    {                                                                         \
        _Pragma("unroll")                                                     \
        for (int s = 0; s < 4; ++s)                                           \
            gload_lds16(Bp + (size_t)((NB) + s * 64 + rsub4) * 512 + (OFF) + l4 * 8, \
                        Bt[BUF] + (size_t)(s * 256 + tid) * 8);               \
    }
#define MSTEP(RA, RB)                                                         \
    {                                                                         \
        const u16* Eb = Bt[RB] + (wcg * 128 + lr) * 32 + ((lg ^ key) * 8);    \
        const u16* Zb = At[RA] + (wrg * 64 + lr) * 32 + ((lg ^ key) * 8);     \
        bf16x8 a[8], b[4];                                                    \
        _Pragma("unroll")                                                     \
        for (int fr = 0; fr < 8; ++fr)                                        \
            a[fr] = *reinterpret_cast<const bf16x8*>(Eb + fr * 512);          \
        _Pragma("unroll")                                                     \
        for (int fc = 0; fc < 4; ++fc)                                        \
            b[fc] = *reinterpret_cast<const bf16x8*>(Zb + fc * 512);          \
        _Pragma("unroll")                                                     \
        for (int fr = 0; fr < 8; ++fr)                                        \
            _Pragma("unroll")                                                 \
            for (int fc = 0; fc < 4; ++fc)                                    \
                acc[fr][fc] = __builtin_amdgcn_mfma_f32_16x16x32_bf16(        \
                    a[fr], b[fc], acc[fr][fc], 0, 0, 0);                      \
    }

    // persistent per-lane top-3 state: slot = fc (z-row = wrg*64 + fc*16 + lr)
    float v1[4], v2[4], v3[4];
    unsigned pidx[4];
#pragma unroll
    for (int s = 0; s < 4; ++s) { v1[s] = FLT_MAX; v2[s] = FLT_MAX; v3[s] = FLT_MAX; pidx[s] = 0; }

    f32x4 acc[8][4];                       // [fr=code frag][fc=z frag]

    // ---- prologue: zhi chunk0 -> A0, ehi(nc=0) chunk0 -> B0; drain; barrier ----
    SAT(0, zhi, 0);
    SBT(0, 0, 0);
    WAITVM(0);
    RBAR();

#pragma unroll 1
    for (int nc = 0; nc < 4; ++nc) {           // code chunks of 256
        const int n0 = nc * 256;
#pragma unroll
        for (int fr = 0; fr < 8; ++fr)
#pragma unroll
            for (int fc = 0; fc < 4; ++fc) acc[fr][fc] = (f32x4){0.f, 0.f, 0.f, 0.f};

#pragma unroll
        for (int j = 0; j < 8; ++j) {
            const int xB = j & 1;
            const int c  = j * 32;
            // S1: zhi_j x ehi_j. Stage elo_j -> B(x^1) [4], zlo_j -> A1 [2].
            SBT(xB ^ 1, n0, 256 + c);
            SAT(1, zlo, c);
            WAITVM(6); RBAR(); MSTEP(0, xB); RBAR();
            // S2: zhi_j x elo_j. (zlo still in flight: wait to 2.)
            WAITVM(2); RBAR(); MSTEP(0, xB ^ 1); RBAR();
            // S3: zlo_j x ehi_j. Stage zhi_next -> A0 [2], ehi_next -> B(x^1) [4].
            if (j < 7) {
                SAT(0, zhi, c + 32);
                SBT(xB ^ 1, n0, c + 32);
                WAITVM(6);
            } else if (nc < 3) {
                SAT(0, zhi, 0);
                SBT(xB ^ 1, n0 + 256, 0);
                WAITVM(6);
            } else {
                WAITVM(0);
            }
            RBAR(); MSTEP(1, xB); RBAR();
        }

        // ---- register-local scan (overlaps next-nc in-flight loads) ----
#pragma unroll
        for (int fr = 0; fr < 8; ++fr) {
            const int cbase = n0 + wcg * 128 + fr * 16 + lg * 4;
            const float4 e2v = *reinterpret_cast<const float4*>(&e2s[cbase]);
#pragma unroll
            for (int q = 0; q < 4; ++q) {
                const unsigned n = (unsigned)(cbase + q);
                const float e2q = (q == 0) ? e2v.x : (q == 1) ? e2v.y : (q == 2) ? e2v.z : e2v.w;
#pragma unroll
                for (int fc = 0; fc < 4; ++fc) {
                    float d = __fmaf_rn(-2.0f, acc[fr][fc][q], e2q);
                    bool lt1 = d < v1[fc];
                    bool lt2 = d < v2[fc];
                    bool lt3 = d < v3[fc];
                    v3[fc] = lt2 ? v2[fc] : (lt3 ? d : v3[fc]);
                    v2[fc] = lt1 ? v1[fc] : (lt2 ? d : v2[fc]);
                    pidx[fc] = lt1 ? ((pidx[fc] << 16) | n)
                                   : (lt2 ? ((pidx[fc] & 0xffffu) | (n << 16)) : pidx[fc]);
                    v1[fc] = lt1 ? d : v1[fc];
                }
            }
        }
    }

    // ---- ONE butterfly per slot across lg groups (masks 16, 32) ----
#pragma unroll
    for (int s = 0; s < 4; ++s) {
        float a1 = v1[s], a2 = v2[s], a3 = v3[s];
        int ai1 = (int)(pidx[s] & 0xffffu), ai2 = (int)(pidx[s] >> 16);
#pragma unroll
        for (int m = 16; m <= 32; m <<= 1) {
            float b1 = __shfl_xor(a1, m), b2 = __shfl_xor(a2, m), b3 = __shfl_xor(a3, m);
            int bi1 = __shfl_xor(ai1, m), bi2 = __shfl_xor(ai2, m);
            MERGE5(a1, ai1, a2, ai2, a3, b1, bi1, b2, bi2, b3);
        }
        if (lg == 0) {
            int row = wrg * 64 + s * 16 + lr;
            float* p = &mrg[(row * 2 + wcg) * 4];
            p[0] = a1; p[1] = a2; p[2] = a3;
            p[3] = __uint_as_float(((unsigned)ai1 & 0xffffu) | ((unsigned)ai2 << 16));
        }
    }
    __syncthreads();

    if (tid < 128) {
        const float* p0 = &mrg[(tid * 2 + 0) * 4];
        float A1 = p0[0], A2 = p0[1], A3 = p0[2];
        unsigned pk = __float_as_uint(p0[3]);
        int I1 = (int)(pk & 0xffffu), I2 = (int)(pk >> 16);
        const float* p = &mrg[(tid * 2 + 1) * 4];
        float b1 = p[0], b2 = p[1], b3 = p[2];
        unsigned q = __float_as_uint(p[3]);
        int bi1 = (int)(q & 0xffffu), bi2 = (int)(q >> 16);
        MERGE5(A1, I1, A2, I2, A3, b1, bi1, b2, bi2, b3);
        ci1[m0 + tid] = I1;
        ci2[m0 + tid] = I2;
        cflag[m0 + tid] = (A3 - A1 <= DELTA) ? 1 : 0;
    }
}

// ---------- exact fp32 distance (verified r3 chain) ----------
__device__ __forceinline__ float exact_g(const float* __restrict__ zr,
                                         const float* __restrict__ er,
                                         float z2v, float e2v) {
    float m = 0.f;
    for (int k = 0; k < 256; k += 4) {
        float4 zv = *reinterpret_cast<const float4*>(zr + k);
        float4 ev = *reinterpret_cast<const float4*>(er + k);
        m = __fmaf_rn(zv.x, ev.x, m);
        m = __fmaf_rn(zv.y, ev.y, m);
        m = __fmaf_rn(zv.z, ev.z, m);
        m = __fmaf_rn(zv.w, ev.w, m);
    }
    return __fsub_rn(__fadd_rn(z2v, e2v), __fmul_rn(2.0f, m));
}

// ---------- K3: exact top-2 refine + zq/loss for unflagged rows ----------
__global__ __launch_bounds__(256)
void vq_refine_kernel(const float* __restrict__ z, const float* __restrict__ e,
                      const float* __restrict__ z2g, const float* __restrict__ e2f,
                      const int* __restrict__ ci1, const int* __restrict__ ci2,
                      const int* __restrict__ cflag,
                      float* __restrict__ out_idx, int* __restrict__ list,
                      int* __restrict__ counter,
                      float* __restrict__ out_zq, double* __restrict__ partials) {
    __shared__ float  gbuf[128];
    __shared__ int    fIdx[64];
    __shared__ int    fFlag[64];
    __shared__ double dred[256];
    const int tid = threadIdx.x;
    const int r0  = blockIdx.x * 64;

    if (tid < 128) {
        int r = tid >> 1, which = tid & 1;
        int row = r0 + r;
        int c = which ? ci2[row] : ci1[row];
        gbuf[tid] = exact_g(z + (size_t)row * EDIM, e + (size_t)c * EDIM, z2g[row], e2f[c]);
    }
    __syncthreads();
    if (tid < 64) {
        int row = r0 + tid;
        int a = ci1[row], b = ci2[row];
        float ga = gbuf[tid * 2], gb = gbuf[tid * 2 + 1];
        int fi = (gb < ga || (gb == ga && b < a)) ? b : a;
        fIdx[tid] = fi;
        int fl = cflag[row];
        fFlag[tid] = fl;
        out_idx[row] = (float)fi;
        if (fl) { int p = atomicAdd(counter, 1); list[p] = row; }
    }
    __syncthreads();

    double lsum = 0.0;
    for (int r = 0; r < 64; ++r) {
        if (!fFlag[r]) {
            int row = r0 + r;
            float zv = z[(size_t)row * EDIM + tid];
            float ev = e[(size_t)fIdx[r] * EDIM + tid];
            float dd = __fsub_rn(ev, zv);
            out_zq[(size_t)row * EDIM + tid] = __fadd_rn(zv, dd);
            lsum += (double)dd * (double)dd;
        }
    }
    dred[tid] = lsum;
    __syncthreads();
#pragma unroll
    for (int s = 128; s > 0; s >>= 1) {
        if (tid < s) dred[tid] += dred[tid + s];
        __syncthreads();
    }
    if (tid == 0) partials[blockIdx.x] = dred[0];
}

// ---------- K3b: full exact rescan for flagged rows ----------
__global__ __launch_bounds__(256)
void vq_fallback_kernel(const float* __restrict__ z, const float* __restrict__ e,
                        const float* __restrict__ z2g, const float* __restrict__ e2f,
                        const int* __restrict__ list, const int* __restrict__ counter,
                        float* __restrict__ out_idx, float* __restrict__ out_zq,
                        double* __restrict__ partials2) {
    __shared__ float  elds[64 * 257];
    __shared__ float  zlds[4][256];
    __shared__ float  z2s[4];
    __shared__ double dred[256];
    const int n   = *counter;
    const int tid = threadIdx.x;
    const int w   = tid >> 6;
    const int lane = tid & 63;
    double lsum = 0.0;

    for (int base = blockIdx.x * 4; base < n; base += gridDim.x * 4) {
        const int nr = min(4, n - base);
        __syncthreads();
        for (int i = tid; i < nr * 256; i += 256)
            zlds[i >> 8][i & 255] = z[(size_t)list[base + (i >> 8)] * EDIM + (i & 255)];
        if (tid < nr) z2s[tid] = z2g[list[base + tid]];

        float bv = FLT_MAX; int bi = 0x7fffffff;
        const int srow  = ((tid >> 4) & 3);
        const int scolq = (tid & 15) | ((tid >> 6) << 4);
        for (int c0 = 0; c0 < NE; c0 += 64) {
            __syncthreads();
#pragma unroll
            for (int s = 0; s < 16; ++s) {
                int row = 4 * s + srow;
                float4 v = *reinterpret_cast<const float4*>(e + (size_t)(c0 + row) * EDIM + scolq * 4);
                float* d = &elds[row * 257 + scolq * 4];
                d[0] = v.x; d[1] = v.y; d[2] = v.z; d[3] = v.w;
            }
            __syncthreads();
            const int code = c0 + lane;
            const float* er = &elds[lane * 257];
            const float* zr = zlds[w];
            float m = 0.f;
#pragma unroll 8
            for (int k = 0; k < 256; ++k)
                m = __fmaf_rn(zr[k], er[k], m);
            float g = __fsub_rn(__fadd_rn(z2s[w], e2f[code]), __fmul_rn(2.0f, m));
            if (g < bv || (g == bv && code < bi)) { bv = g; bi = code; }
        }
#pragma unroll
        for (int m2 = 1; m2 < 64; m2 <<= 1) {
            float ov = __shfl_xor(bv, m2); int oi = __shfl_xor(bi, m2);
            if (ov < bv || (ov == bv && oi < bi)) { bv = ov; bi = oi; }
        }
        if (w < nr) {
            int row = list[base + w];
            if (lane == 0) out_idx[row] = (float)bi;
            const float* er2 = e + (size_t)bi * EDIM;
            for (int c = lane; c < 256; c += 64) {
                float zv = zlds[w][c];
                float dd = __fsub_rn(er2[c], zv);
                out_zq[(size_t)row * EDIM + c] = __fadd_rn(zv, dd);
                lsum += (double)dd * (double)dd;
            }
        }
    }
    dred[tid] = lsum;
    __syncthreads();
#pragma unroll
    for (int s = 128; s > 0; s >>= 1) {
        if (tid < s) dred[tid] += dred[tid + s];
        __syncthreads();
    }
    if (tid == 0) partials2[blockIdx.x] = dred[0];
}

__global__ void vq_loss_kernel(const double* __restrict__ partials, int count,
                               float* __restrict__ out_loss) {
    __shared__ double s[256];
    const int tid = threadIdx.x;
    double v = 0.0;
    for (int i = tid; i < count; i += 256) v += partials[i];
    s[tid] = v;
    __syncthreads();
    for (int k = 128; k > 0; k >>= 1) {
        if (tid < k) s[tid] += s[tid + k];
        __syncthreads();
    }
    if (tid == 0) {
        double mean = s[0] / ((double)NROWS * (double)EDIM);
        out_loss[0] = (float)(1.25 * mean);
    }
}

// ================= fallback (proven r3 pipeline) if ws too small =================
__global__ __launch_bounds__(256, 2)
void vq_main_r3(const float* __restrict__ z, const float* __restrict__ e,
                const float* __restrict__ z2g, const float* __restrict__ e2g,
                float* __restrict__ out_zq, float* __restrict__ out_idx,
                double* __restrict__ partials) {
    __shared__ float A[BK][BM];
    __shared__ float Bm[BK][BN];
    __shared__ float e2s[BN];
    __shared__ int   fIdx[BM];
    __shared__ double dred[256];
    const int tid = threadIdx.x;
    const int m0 = blockIdx.x * BM;
    const int trow = tid >> 4, tcol = tid & 15;
    float z2r[8];
#pragma unroll
    for (int i = 0; i < 8; ++i) z2r[i] = z2g[m0 + trow * 8 + i];
    float bestV[8]; int bestI[8];
#pragma unroll
    for (int i = 0; i < 8; ++i) { bestV[i] = FLT_MAX; bestI[i] = 0; }
    for (int n0 = 0; n0 < NE; n0 += BN) {
        float acc[8][8];
#pragma unroll
        for (int i = 0; i < 8; ++i)
#pragma unroll
            for (int j = 0; j < 8; ++j) acc[i][j] = 0.f;
        __syncthreads();
        if (tid < BN) e2s[tid] = e2g[n0 + tid];
        for (int k0 = 0; k0 < EDIM; k0 += BK) {
            __syncthreads();
#pragma unroll
            for (int s = 0; s < 4; ++s) {
                int q = tid + 256 * s, row = q >> 3, kc = (q & 7) << 2;
                float4 va = *reinterpret_cast<const float4*>(z + (size_t)(m0 + row) * EDIM + k0 + kc);
                A[kc + 0][row] = va.x; A[kc + 1][row] = va.y; A[kc + 2][row] = va.z; A[kc + 3][row] = va.w;
                float4 vb = *reinterpret_cast<const float4*>(e + (size_t)(n0 + row) * EDIM + k0 + kc);
                Bm[kc + 0][row] = vb.x; Bm[kc + 1][row] = vb.y; Bm[kc + 2][row] = vb.z; Bm[kc + 3][row] = vb.w;
            }
            __syncthreads();
#pragma unroll
            for (int k = 0; k < BK; ++k) {
                float a[8], b[8];
                *reinterpret_cast<float4*>(&a[0]) = *reinterpret_cast<const float4*>(&A[k][trow * 8]);
                *reinterpret_cast<float4*>(&a[4]) = *reinterpret_cast<const float4*>(&A[k][trow * 8 + 4]);
                *reinterpret_cast<float4*>(&b[0]) = *reinterpret_cast<const float4*>(&Bm[k][tcol * 8]);
                *reinterpret_cast<float4*>(&b[4]) = *reinterpret_cast<const float4*>(&Bm[k][tcol * 8 + 4]);
#pragma unroll
                for (int i = 0; i < 8; ++i)
#pragma unroll
                    for (int j = 0; j < 8; ++j) acc[i][j] = __fmaf_rn(a[i], b[j], acc[i][j]);
            }
        }
#pragma unroll
        for (int i = 0; i < 8; ++i)
#pragma unroll
            for (int j = 0; j < 8; ++j) {
                int n = n0 + tcol * 8 + j;
                float d = __fsub_rn(__fadd_rn(z2r[i], e2s[tcol * 8 + j]), __fmul_rn(2.0f, acc[i][j]));
                if (d < bestV[i]) { bestV[i] = d; bestI[i] = n; }
            }
    }
    __syncthreads();
    float* red_v = &A[0][0];
    int* red_i = reinterpret_cast<int*>(&Bm[0][0]);
#pragma unroll
    for (int i = 0; i < 8; ++i) {
        int row = trow * 8 + i;
        red_v[row * 16 + tcol] = bestV[i];
        red_i[row * 16 + tcol] = bestI[i];
    }
    __syncthreads();
    if (tid < BM) {
        float b1 = FLT_MAX; int i1 = 0x7fffffff;
        for (int t = 0; t < 16; ++t) {
            float v = red_v[tid * 16 + t]; int id = red_i[tid * 16 + t];
            if (v < b1 || (v == b1 && id < i1)) { b1 = v; i1 = id; }
        }
        fIdx[tid] = i1;
        out_idx[m0 + tid] = (float)i1;
    }
    __syncthreads();
    double lsum = 0.0;
    for (int r = 0; r < BM; ++r) {
        int fi = fIdx[r];
        float zv = z[(size_t)(m0 + r) * EDIM + tid];
        float ev = e[(size_t)fi * EDIM + tid];
        float dd = __fsub_rn(ev, zv);
        out_zq[(size_t)(m0 + r) * EDIM + tid] = __fadd_rn(zv, dd);
        lsum += (double)dd * (double)dd;
    }
    dred[tid] = lsum;
    __syncthreads();
#pragma unroll
    for (int s = 128; s > 0; s >>= 1) {
        if (tid < s) dred[tid] += dred[tid + s];
        __syncthreads();
    }
    if (tid == 0) partials[blockIdx.x] = dred[0];
}

extern "C" void kernel_launch(void* const* d_in, const int* in_sizes, int n_in,
                              void* d_out, int out_size, void* d_ws, size_t ws_size,
                              hipStream_t stream) {
    (void)n_in; (void)out_size;
    const float* z = (const float*)d_in[0];
    const float* e = (const float*)d_in[1];
    if (in_sizes[0] == NE * EDIM) { const float* t = z; z = e; e = t; }
    float* out      = (float*)d_out;
    float* out_zq   = out;
    float* out_loss = out + (size_t)NROWS * EDIM;
    float* out_idx  = out_loss + 1;

    char* ws = (char*)d_ws;
    float*  z2g      = (float*)(ws + WS_Z2);
    float*  e2f      = (float*)(ws + WS_E2);
    double* partials = (double*)(ws + WS_PART);

    rownorm_kernel<<<(NE + 255) / 256, 256, 0, stream>>>(e, e2f, NE);

    if (ws_size >= WS_END) {
        int* cnt  = (int*)(ws + WS_CNT);
        int* list = (int*)(ws + WS_LIST);
        int* ci1  = (int*)(ws + WS_CI1);
        int* ci2  = (int*)(ws + WS_CI2);
        int* flg  = (int*)(ws + WS_FLG);
        u16* Bp   = (u16*)(ws + WS_BP);
        u16* zhi  = (u16*)d_out;                       // zq region as scratch
        u16* zlo  = zhi + (size_t)NROWS * EDIM;

        hipMemsetAsync(cnt, 0, 4, stream);
        rownorm_split_kernel<<<NROWS / 16, 256, 0, stream>>>(z, z2g, zhi, zlo);
        build_b_kernel<<<NE * EDIM / 256, 256, 0, stream>>>(e, Bp);
        vq_mfma_kernel<<<NROWS / 128, 256, 0, stream>>>(zhi, zlo, Bp, e2f, ci1, ci2, flg);
        vq_refine_kernel<<<NROWS / 64, 256, 0, stream>>>(z, e, z2g, e2f, ci1, ci2, flg,
                                                         out_idx, list, cnt, out_zq, partials);
        vq_fallback_kernel<<<512, 256, 0, stream>>>(z, e, z2g, e2f, list, cnt,
                                                    out_idx, out_zq, partials + 2048);
        vq_loss_kernel<<<1, 256, 0, stream>>>(partials, 2560, out_loss);
    } else {
        rownorm_kernel<<<NROWS / 256, 256, 0, stream>>>(z, z2g, NROWS);
        vq_main_r3<<<NROWS / BM, 256, 0, stream>>>(z, e, z2g, e2f, out_zq, out_idx, partials);
        vq_loss_kernel<<<1, 256, 0, stream>>>(partials, 1024, out_loss);
    }
}

// Round 18
// 574.313 us; speedup vs baseline: 1.2400x; 1.2400x over previous
//
#include <hip/hip_runtime.h>
#include <cfloat>

#define NROWS 131072
#define EDIM 256
#define NE 1024
#define DELTA 2.0e-4f

#define BM 128
#define BN 128
#define BK 32

typedef unsigned short u16;
typedef __attribute__((ext_vector_type(8))) short bf16x8;
typedef __attribute__((ext_vector_type(4))) float f32x4;

// ---- ws layout (bytes) ----
#define WS_Z2    0u
#define WS_E2    524288u
#define WS_PART  528384u        // 2560 doubles (2048 refine + 512 fallback)
#define WS_CNT   548864u
#define WS_LIST  549120u
#define WS_CI1   1073408u
#define WS_CI2   1597696u
#define WS_FLG   2121984u
#define WS_BP    2646272u
#define WS_END   4219136u

// ---------- numpy pairwise sum-of-squares (256 elems), serial form ----------
__device__ __forceinline__ float np_sumsq256(const float* __restrict__ row) {
    float s[2];
#pragma unroll
    for (int h = 0; h < 2; ++h) {
        const float* a = row + h * 128;
        float r[8];
#pragma unroll
        for (int j = 0; j < 8; ++j) r[j] = __fmul_rn(a[j], a[j]);
        for (int i = 8; i < 128; i += 8) {
#pragma unroll
            for (int j = 0; j < 8; ++j)
                r[j] = __fadd_rn(r[j], __fmul_rn(a[i + j], a[i + j]));
        }
        s[h] = __fadd_rn(__fadd_rn(__fadd_rn(r[0], r[1]), __fadd_rn(r[2], r[3])),
                         __fadd_rn(__fadd_rn(r[4], r[5]), __fadd_rn(r[6], r[7])));
    }
    return __fadd_rn(s[0], s[1]);
}

__device__ __forceinline__ u16 bf16_rn(float x) {
    unsigned u = __float_as_uint(x);
    return (u16)((u + 0x7fffu + ((u >> 16) & 1u)) >> 16);
}

// ---------- fused, COALESCED: z2 (numpy-pairwise via shfl tree) + z->zhi/zlo ----------
__global__ __launch_bounds__(256)
void rownorm_split_kernel(const float* __restrict__ z, float* __restrict__ z2out,
                          u16* __restrict__ zhi, u16* __restrict__ zlo) {
    __shared__ float zl[16 * 256];   // 16 KiB
    const int tid = threadIdx.x;
    const size_t base4 = (size_t)blockIdx.x * 1024;   // float4 index of block base

    {
        const float4* src = reinterpret_cast<const float4*>(z) + base4;
        float4* dst = reinterpret_cast<float4*>(zl);
#pragma unroll
        for (int i = 0; i < 4; ++i) dst[tid + 256 * i] = src[tid + 256 * i];
    }
    __syncthreads();

    {
        const int row = tid >> 4;
        const int j16 = tid & 15;
        const int h = j16 >> 3, j = j16 & 7;
        const float* a = &zl[row * 256 + h * 128];
        float r = __fmul_rn(a[j], a[j]);
#pragma unroll
        for (int i = 8; i < 128; i += 8)
            r = __fadd_rn(r, __fmul_rn(a[i + j], a[i + j]));
        r = __fadd_rn(r, __shfl_xor(r, 1));
        r = __fadd_rn(r, __shfl_xor(r, 2));
        r = __fadd_rn(r, __shfl_xor(r, 4));   // = s[h]
        r = __fadd_rn(r, __shfl_xor(r, 8));   // = s[0]+s[1]
        if (j16 == 0) z2out[blockIdx.x * 16 + row] = r;
    }

    {
        ushort4* ph = reinterpret_cast<ushort4*>(zhi) + base4;
        ushort4* pl = reinterpret_cast<ushort4*>(zlo) + base4;
        const float4* sp = reinterpret_cast<const float4*>(zl);
#pragma unroll
        for (int i = 0; i < 4; ++i) {
            const int q = tid + 256 * i;
            float4 v = sp[q];
            float xs[4] = {v.x, v.y, v.z, v.w};
            u16 hh[4], lo[4];
#pragma unroll
            for (int c = 0; c < 4; ++c) {
                u16 hv = bf16_rn(xs[c]);
                float hf = __uint_as_float(((unsigned)hv) << 16);
                hh[c] = hv;
                lo[c] = bf16_rn(__fsub_rn(xs[c], hf));
            }
            ph[q] = make_ushort4(hh[0], hh[1], hh[2], hh[3]);
            pl[q] = make_ushort4(lo[0], lo[1], lo[2], lo[3]);
        }
    }
}

__global__ __launch_bounds__(256)
void rownorm_kernel(const float* __restrict__ x, float* __restrict__ out, int nrows) {
    int row = blockIdx.x * blockDim.x + threadIdx.x;
    if (row < nrows) out[row] = np_sumsq256(x + (size_t)row * EDIM);
}

// B' layout: [e_hi | e_lo], stride 512 per code row
__global__ __launch_bounds__(256)
void build_b_kernel(const float* __restrict__ e, u16* __restrict__ Bp) {
    int idx = blockIdx.x * 256 + threadIdx.x;
    int row = idx >> 8, k = idx & 255;
    float x = e[idx];
    u16 hh = bf16_rn(x);
    float hf = __uint_as_float(((unsigned)hh) << 16);
    u16 lo = bf16_rn(__fsub_rn(x, hf));
    Bp[row * 512 + k] = hh;
    Bp[row * 512 + 256 + k] = lo;
}

__device__ __forceinline__ void gload_lds16(const void* g, void* lds) {
    __builtin_amdgcn_global_load_lds((const __attribute__((address_space(1))) void*)g,
                                     (__attribute__((address_space(3))) void*)lds,
                                     16, 0, 0);
}

#define LEXLT(va, ia, vb, ib) ((va) < (vb) || ((va) == (vb) && (ia) < (ib)))

#define MERGE5(a1, ai1, a2, ai2, a3, b1, bi1, b2, bi2, b3)                    \
    {                                                                         \
        float n1v, n2v, n3v; int n1i, n2i;                                    \
        if (LEXLT(a1, ai1, b1, bi1)) {                                        \
            n1v = a1; n1i = ai1;                                              \
            if (LEXLT(a2, ai2, b1, bi1)) { n2v = a2; n2i = ai2; n3v = fminf(a3, b1); } \
            else                          { n2v = b1; n2i = bi1; n3v = fminf(a2, b2); } \
        } else {                                                              \
            n1v = b1; n1i = bi1;                                              \
            if (LEXLT(b2, bi2, a1, ai1)) { n2v = b2; n2i = bi2; n3v = fminf(b3, a1); } \
            else                          { n2v = a1; n2i = ai1; n3v = fminf(b2, a2); } \
        }                                                                     \
        a1 = n1v; ai1 = n1i; a2 = n2v; ai2 = n2i; a3 = n3v;                   \
    }

#define WAITVM(N) asm volatile("s_waitcnt vmcnt(" #N ")" ::: "memory")
#define RBAR()    asm volatile("s_barrier" ::: "memory")

// ---------- K2: bf16 MFMA, D[code][z-row], tile 128z x 128codes, fr4 x fc4,
//            32-col chunks, double-buffered, counted-vmcnt pipeline ----------
// 256 thr / 4 waves (wrg 0..1 z-groups x wcg 0..1 code-groups).
// LDS 40 KiB -> 3 blocks/CU; acc 64 AGPR + ~90 arch VGPR -> 3 waves/SIMD.
// Per (nc, j): S1 zhi x ehi, S2 zhi x elo, S3 zlo x ehi; 2-load stages,
// waits 4/2/4 (never 0 mid-loop); ehi staged once, read twice.
__global__ __launch_bounds__(256, 3)
void vq_mfma_kernel(const u16* __restrict__ zhi, const u16* __restrict__ zlo,
                    const u16* __restrict__ Bp, const float* __restrict__ e2f,
                    int* __restrict__ ci1, int* __restrict__ ci2, int* __restrict__ cflag) {
    __shared__ __align__(16) u16  At[2][128 * 32];  // 2 x 8 KiB (z col-chunk)
    __shared__ __align__(16) u16  Bt[2][128 * 32];  // 2 x 8 KiB (codes col-chunk)
    __shared__ float e2s[1024];                     // 4 KiB
    __shared__ float mrg[128 * 2 * 4];              // 4 KiB [row][wcg][v1,v2,v3,pk]

    const int tid = threadIdx.x;
    const int m0  = blockIdx.x * 128;
    const int l   = tid & 63;
    const int wid = tid >> 6;
    const int wrg = wid >> 1;       // 0..1 -> z-rows wrg*64
    const int wcg = wid & 1;        // 0..1 -> codes wcg*64 (within 128-chunk)
    const int lr  = l & 15;
    const int lg  = l >> 4;         // 0..3
    const int key = lr & 3;         // 4 chunks of 16B per 32-col row

#pragma unroll
    for (int i = 0; i < 4; ++i) e2s[tid + 256 * i] = e2f[tid + 256 * i];

    // staging map: chunk c = s*256+tid; row = s*64 + (tid>>2); phys = tid&3
    const int rsub4 = tid >> 2;                  // 0..63
    const int l4    = (tid & 3) ^ (rsub4 & 3);   // logical 16B chunk at this slot

#define SAT(BUF, SRC, COLC)                                                   \
    {                                                                         \
        _Pragma("unroll")                                                     \
        for (int s = 0; s < 2; ++s)                                           \
            gload_lds16((SRC) + (size_t)(m0 + s * 64 + rsub4) * 256 + (COLC) + l4 * 8, \
                        At[BUF] + (size_t)(s * 256 + tid) * 8);               \
    }
#define SBT(BUF, NB, OFF)                                                     \
    {                                                                         \
        _Pragma("unroll")                                                     \
        for (int s = 0; s < 2; ++s)                                           \
            gload_lds16(Bp + (size_t)((NB) + s * 64 + rsub4) * 512 + (OFF) + l4 * 8, \
                        Bt[BUF] + (size_t)(s * 256 + tid) * 8);               \
    }
#define MSTEP(RA, RB)                                                         \
    {                                                                         \
        const u16* Eb = Bt[RB] + (wcg * 64 + lr) * 32 + ((lg ^ key) * 8);     \
        const u16* Zb = At[RA] + (wrg * 64 + lr) * 32 + ((lg ^ key) * 8);     \
        bf16x8 a[4], b[4];                                                    \
        _Pragma("unroll")                                                     \
        for (int fr = 0; fr < 4; ++fr)                                        \
            a[fr] = *reinterpret_cast<const bf16x8*>(Eb + fr * 512);          \
        _Pragma("unroll")                                                     \
        for (int fc = 0; fc < 4; ++fc)                                        \
            b[fc] = *reinterpret_cast<const bf16x8*>(Zb + fc * 512);          \
        _Pragma("unroll")                                                     \
        for (int fr = 0; fr < 4; ++fr)                                        \
            _Pragma("unroll")                                                 \
            for (int fc = 0; fc < 4; ++fc)                                    \
                acc[fr][fc] = __builtin_amdgcn_mfma_f32_16x16x32_bf16(        \
                    a[fr], b[fc], acc[fr][fc], 0, 0, 0);                      \
    }

    // persistent per-lane top-3 state: slot = fc (z-row = wrg*64 + fc*16 + lr)
    float v1[4], v2[4], v3[4];
    unsigned pidx[4];
#pragma unroll
    for (int s = 0; s < 4; ++s) { v1[s] = FLT_MAX; v2[s] = FLT_MAX; v3[s] = FLT_MAX; pidx[s] = 0; }

    f32x4 acc[4][4];                       // [fr=code frag][fc=z frag]

    // ---- prologue: zhi chunk0 -> A0, ehi(nc=0) chunk0 -> B0; drain; barrier ----
    SAT(0, zhi, 0);
    SBT(0, 0, 0);
    WAITVM(0);
    RBAR();

#pragma unroll 1
    for (int nc = 0; nc < 8; ++nc) {           // code chunks of 128
        const int n0 = nc * 128;
#pragma unroll
        for (int fr = 0; fr < 4; ++fr)
#pragma unroll
            for (int fc = 0; fc < 4; ++fc) acc[fr][fc] = (f32x4){0.f, 0.f, 0.f, 0.f};

#pragma unroll 2
        for (int j = 0; j < 8; ++j) {
            const int xB = j & 1;
            const int c  = j * 32;
            // S1: zhi_j x ehi_j. Stage elo_j -> B(x^1) [2], zlo_j -> A1 [2].
            SBT(xB ^ 1, n0, 256 + c);
            SAT(1, zlo, c);
            WAITVM(4); RBAR(); MSTEP(0, xB); RBAR();
            // S2: zhi_j x elo_j. (zlo still in flight: wait to 2.)
            WAITVM(2); RBAR(); MSTEP(0, xB ^ 1); RBAR();
            // S3: zlo_j x ehi_j. Stage zhi_next -> A0 [2], ehi_next -> B(x^1) [2].
            if (j < 7) {
                SAT(0, zhi, c + 32);
                SBT(xB ^ 1, n0, c + 32);
                WAITVM(4);
            } else if (nc < 7) {
                SAT(0, zhi, 0);
                SBT(xB ^ 1, n0 + 128, 0);
                WAITVM(4);
            } else {
                WAITVM(0);
            }
            RBAR(); MSTEP(1, xB); RBAR();
        }

        // ---- register-local scan (overlaps next-nc in-flight loads) ----
#pragma unroll
        for (int fr = 0; fr < 4; ++fr) {
            const int cbase = n0 + wcg * 64 + fr * 16 + lg * 4;
            const float4 e2v = *reinterpret_cast<const float4*>(&e2s[cbase]);
#pragma unroll
            for (int q = 0; q < 4; ++q) {
                const unsigned n = (unsigned)(cbase + q);
                const float e2q = (q == 0) ? e2v.x : (q == 1) ? e2v.y : (q == 2) ? e2v.z : e2v.w;
#pragma unroll
                for (int fc = 0; fc < 4; ++fc) {
                    float d = __fmaf_rn(-2.0f, acc[fr][fc][q], e2q);
                    bool lt1 = d < v1[fc];
                    bool lt2 = d < v2[fc];
                    bool lt3 = d < v3[fc];
                    v3[fc] = lt2 ? v2[fc] : (lt3 ? d : v3[fc]);
                    v2[fc] = lt1 ? v1[fc] : (lt2 ? d : v2[fc]);
                    pidx[fc] = lt1 ? ((pidx[fc] << 16) | n)
                                   : (lt2 ? ((pidx[fc] & 0xffffu) | (n << 16)) : pidx[fc]);
                    v1[fc] = lt1 ? d : v1[fc];
                }
            }
        }
    }

    // ---- ONE butterfly per slot across lg groups (masks 16, 32) ----
#pragma unroll
    for (int s = 0; s < 4; ++s) {
        float a1 = v1[s], a2 = v2[s], a3 = v3[s];
        int ai1 = (int)(pidx[s] & 0xffffu), ai2 = (int)(pidx[s] >> 16);
#pragma unroll
        for (int m = 16; m <= 32; m <<= 1) {
            float b1 = __shfl_xor(a1, m), b2 = __shfl_xor(a2, m), b3 = __shfl_xor(a3, m);
            int bi1 = __shfl_xor(ai1, m), bi2 = __shfl_xor(ai2, m);
            MERGE5(a1, ai1, a2, ai2, a3, b1, bi1, b2, bi2, b3);
        }
        if (lg == 0) {
            int row = wrg * 64 + s * 16 + lr;
            float* p = &mrg[(row * 2 + wcg) * 4];
            p[0] = a1; p[1] = a2; p[2] = a3;
            p[3] = __uint_as_float(((unsigned)ai1 & 0xffffu) | ((unsigned)ai2 << 16));
        }
    }
    __syncthreads();

    if (tid < 128) {
        const float* p0 = &mrg[(tid * 2 + 0) * 4];
        float A1 = p0[0], A2 = p0[1], A3 = p0[2];
        unsigned pk = __float_as_uint(p0[3]);
        int I1 = (int)(pk & 0xffffu), I2 = (int)(pk >> 16);
        const float* p = &mrg[(tid * 2 + 1) * 4];
        float b1 = p[0], b2 = p[1], b3 = p[2];
        unsigned q = __float_as_uint(p[3]);
        int bi1 = (int)(q & 0xffffu), bi2 = (int)(q >> 16);
        MERGE5(A1, I1, A2, I2, A3, b1, bi1, b2, bi2, b3);
        ci1[m0 + tid] = I1;
        ci2[m0 + tid] = I2;
        cflag[m0 + tid] = (A3 - A1 <= DELTA) ? 1 : 0;
    }
}

// ---------- exact fp32 distance (verified r3 chain) ----------
__device__ __forceinline__ float exact_g(const float* __restrict__ zr,
                                         const float* __restrict__ er,
                                         float z2v, float e2v) {
    float m = 0.f;
    for (int k = 0; k < 256; k += 4) {
        float4 zv = *reinterpret_cast<const float4*>(zr + k);
        float4 ev = *reinterpret_cast<const float4*>(er + k);
        m = __fmaf_rn(zv.x, ev.x, m);
        m = __fmaf_rn(zv.y, ev.y, m);
        m = __fmaf_rn(zv.z, ev.z, m);
        m = __fmaf_rn(zv.w, ev.w, m);
    }
    return __fsub_rn(__fadd_rn(z2v, e2v), __fmul_rn(2.0f, m));
}

// ---------- K3: exact top-2 refine + zq/loss for unflagged rows ----------
__global__ __launch_bounds__(256)
void vq_refine_kernel(const float* __restrict__ z, const float* __restrict__ e,
                      const float* __restrict__ z2g, const float* __restrict__ e2f,
                      const int* __restrict__ ci1, const int* __restrict__ ci2,
                      const int* __restrict__ cflag,
                      float* __restrict__ out_idx, int* __restrict__ list,
                      int* __restrict__ counter,
                      float* __restrict__ out_zq, double* __restrict__ partials) {
    __shared__ float  gbuf[128];
    __shared__ int    fIdx[64];
    __shared__ int    fFlag[64];
    __shared__ double dred[256];
    const int tid = threadIdx.x;
    const int r0  = blockIdx.x * 64;

    if (tid < 128) {
        int r = tid >> 1, which = tid & 1;
        int row = r0 + r;
        int c = which ? ci2[row] : ci1[row];
        gbuf[tid] = exact_g(z + (size_t)row * EDIM, e + (size_t)c * EDIM, z2g[row], e2f[c]);
    }
    __syncthreads();
    if (tid < 64) {
        int row = r0 + tid;
        int a = ci1[row], b = ci2[row];
        float ga = gbuf[tid * 2], gb = gbuf[tid * 2 + 1];
        int fi = (gb < ga || (gb == ga && b < a)) ? b : a;
        fIdx[tid] = fi;
        int fl = cflag[row];
        fFlag[tid] = fl;
        out_idx[row] = (float)fi;
        if (fl) { int p = atomicAdd(counter, 1); list[p] = row; }
    }
    __syncthreads();

    double lsum = 0.0;
    for (int r = 0; r < 64; ++r) {
        if (!fFlag[r]) {
            int row = r0 + r;
            float zv = z[(size_t)row * EDIM + tid];
            float ev = e[(size_t)fIdx[r] * EDIM + tid];
            float dd = __fsub_rn(ev, zv);
            out_zq[(size_t)row * EDIM + tid] = __fadd_rn(zv, dd);
            lsum += (double)dd * (double)dd;
        }
    }
    dred[tid] = lsum;
    __syncthreads();
#pragma unroll
    for (int s = 128; s > 0; s >>= 1) {
        if (tid < s) dred[tid] += dred[tid + s];
        __syncthreads();
    }
    if (tid == 0) partials[blockIdx.x] = dred[0];
}

// ---------- K3b: full exact rescan for flagged rows ----------
__global__ __launch_bounds__(256)
void vq_fallback_kernel(const float* __restrict__ z, const float* __restrict__ e,
                        const float* __restrict__ z2g, const float* __restrict__ e2f,
                        const int* __restrict__ list, const int* __restrict__ counter,
                        float* __restrict__ out_idx, float* __restrict__ out_zq,
                        double* __restrict__ partials2) {
    __shared__ float  elds[64 * 257];
    __shared__ float  zlds[4][256];
    __shared__ float  z2s[4];
    __shared__ double dred[256];
    const int n   = *counter;
    const int tid = threadIdx.x;
    const int w   = tid >> 6;
    const int lane = tid & 63;
    double lsum = 0.0;

    for (int base = blockIdx.x * 4; base < n; base += gridDim.x * 4) {
        const int nr = min(4, n - base);
        __syncthreads();
        for (int i = tid; i < nr * 256; i += 256)
            zlds[i >> 8][i & 255] = z[(size_t)list[base + (i >> 8)] * EDIM + (i & 255)];
        if (tid < nr) z2s[tid] = z2g[list[base + tid]];

        float bv = FLT_MAX; int bi = 0x7fffffff;
        const int srow  = ((tid >> 4) & 3);
        const int scolq = (tid & 15) | ((tid >> 6) << 4);
        for (int c0 = 0; c0 < NE; c0 += 64) {
            __syncthreads();
#pragma unroll
            for (int s = 0; s < 16; ++s) {
                int row = 4 * s + srow;
                float4 v = *reinterpret_cast<const float4*>(e + (size_t)(c0 + row) * EDIM + scolq * 4);
                float* d = &elds[row * 257 + scolq * 4];
                d[0] = v.x; d[1] = v.y; d[2] = v.z; d[3] = v.w;
            }
            __syncthreads();
            const int code = c0 + lane;
            const float* er = &elds[lane * 257];
            const float* zr = zlds[w];
            float m = 0.f;
#pragma unroll 8
            for (int k = 0; k < 256; ++k)
                m = __fmaf_rn(zr[k], er[k], m);
            float g = __fsub_rn(__fadd_rn(z2s[w], e2f[code]), __fmul_rn(2.0f, m));
            if (g < bv || (g == bv && code < bi)) { bv = g; bi = code; }
        }
#pragma unroll
        for (int m2 = 1; m2 < 64; m2 <<= 1) {
            float ov = __shfl_xor(bv, m2); int oi = __shfl_xor(bi, m2);
            if (ov < bv || (ov == bv && oi < bi)) { bv = ov; bi = oi; }
        }
        if (w < nr) {
            int row = list[base + w];
            if (lane == 0) out_idx[row] = (float)bi;
            const float* er2 = e + (size_t)bi * EDIM;
            for (int c = lane; c < 256; c += 64) {
                float zv = zlds[w][c];
                float dd = __fsub_rn(er2[c], zv);
                out_zq[(size_t)row * EDIM + c] = __fadd_rn(zv, dd);
                lsum += (double)dd * (double)dd;
            }
        }
    }
    dred[tid] = lsum;
    __syncthreads();
#pragma unroll
    for (int s = 128; s > 0; s >>= 1) {
        if (tid < s) dred[tid] += dred[tid + s];
        __syncthreads();
    }
    if (tid == 0) partials2[blockIdx.x] = dred[0];
}

__global__ void vq_loss_kernel(const double* __restrict__ partials, int count,
                               float* __restrict__ out_loss) {
    __shared__ double s[256];
    const int tid = threadIdx.x;
    double v = 0.0;
    for (int i = tid; i < count; i += 256) v += partials[i];
    s[tid] = v;
    __syncthreads();
    for (int k = 128; k > 0; k >>= 1) {
        if (tid < k) s[tid] += s[tid + k];
        __syncthreads();
    }
    if (tid == 0) {
        double mean = s[0] / ((double)NROWS * (double)EDIM);
        out_loss[0] = (float)(1.25 * mean);
    }
}

// ================= fallback (proven r3 pipeline) if ws too small =================
__global__ __launch_bounds__(256, 2)
void vq_main_r3(const float* __restrict__ z, const float* __restrict__ e,
                const float* __restrict__ z2g, const float* __restrict__ e2g,
                float* __restrict__ out_zq, float* __restrict__ out_idx,
                double* __restrict__ partials) {
    __shared__ float A[BK][BM];
    __shared__ float Bm[BK][BN];
    __shared__ float e2s[BN];
    __shared__ int   fIdx[BM];
    __shared__ double dred[256];
    const int tid = threadIdx.x;
    const int m0 = blockIdx.x * BM;
    const int trow = tid >> 4, tcol = tid & 15;
    float z2r[8];
#pragma unroll
    for (int i = 0; i < 8; ++i) z2r[i] = z2g[m0 + trow * 8 + i];
    float bestV[8]; int bestI[8];
#pragma unroll
    for (int i = 0; i < 8; ++i) { bestV[i] = FLT_MAX; bestI[i] = 0; }
    for (int n0 = 0; n0 < NE; n0 += BN) {
        float acc[8][8];
#pragma unroll
        for (int i = 0; i < 8; ++i)
#pragma unroll
            for (int j = 0; j < 8; ++j) acc[i][j] = 0.f;
        __syncthreads();
        if (tid < BN) e2s[tid] = e2g[n0 + tid];
        for (int k0 = 0; k0 < EDIM; k0 += BK) {
            __syncthreads();
#pragma unroll
            for (int s = 0; s < 4; ++s) {
                int q = tid + 256 * s, row = q >> 3, kc = (q & 7) << 2;
                float4 va = *reinterpret_cast<const float4*>(z + (size_t)(m0 + row) * EDIM + k0 + kc);
                A[kc + 0][row] = va.x; A[kc + 1][row] = va.y; A[kc + 2][row] = va.z; A[kc + 3][row] = va.w;
                float4 vb = *reinterpret_cast<const float4*>(e + (size_t)(n0 + row) * EDIM + k0 + kc);
                Bm[kc + 0][row] = vb.x; Bm[kc + 1][row] = vb.y; Bm[kc + 2][row] = vb.z; Bm[kc + 3][row] = vb.w;
            }
            __syncthreads();
#pragma unroll
            for (int k = 0; k < BK; ++k) {
                float a[8], b[8];
                *reinterpret_cast<float4*>(&a[0]) = *reinterpret_cast<const float4*>(&A[k][trow * 8]);
                *reinterpret_cast<float4*>(&a[4]) = *reinterpret_cast<const float4*>(&A[k][trow * 8 + 4]);
                *reinterpret_cast<float4*>(&b[0]) = *reinterpret_cast<const float4*>(&Bm[k][tcol * 8]);
                *reinterpret_cast<float4*>(&b[4]) = *reinterpret_cast<const float4*>(&Bm[k][tcol * 8 + 4]);
#pragma unroll
                for (int i = 0; i < 8; ++i)
#pragma unroll
                    for (int j = 0; j < 8; ++j) acc[i][j] = __fmaf_rn(a[i], b[j], acc[i][j]);
            }
        }
#pragma unroll
        for (int i = 0; i < 8; ++i)
#pragma unroll
            for (int j = 0; j < 8; ++j) {
                int n = n0 + tcol * 8 + j;
                float d = __fsub_rn(__fadd_rn(z2r[i], e2s[tcol * 8 + j]), __fmul_rn(2.0f, acc[i][j]));
                if (d < bestV[i]) { bestV[i] = d; bestI[i] = n; }
            }
    }
    __syncthreads();
    float* red_v = &A[0][0];
    int* red_i = reinterpret_cast<int*>(&Bm[0][0]);
#pragma unroll
    for (int i = 0; i < 8; ++i) {
        int row = trow * 8 + i;
        red_v[row * 16 + tcol] = bestV[i];
        red_i[row * 16 + tcol] = bestI[i];
    }
    __syncthreads();
    if (tid < BM) {
        float b1 = FLT_MAX; int i1 = 0x7fffffff;
        for (int t = 0; t < 16; ++t) {
            float v = red_v[tid * 16 + t]; int id = red_i[tid * 16 + t];
            if (v < b1 || (v == b1 && id < i1)) { b1 = v; i1 = id; }
        }
        fIdx[tid] = i1;
        out_idx[m0 + tid] = (float)i1;
    }
    __syncthreads();
    double lsum = 0.0;
    for (int r = 0; r < BM; ++r) {
        int fi = fIdx[r];
        float zv = z[(size_t)(m0 + r) * EDIM + tid];
        float ev = e[(size_t)fi * EDIM + tid];
        float dd = __fsub_rn(ev, zv);
        out_zq[(size_t)(m0 + r) * EDIM + tid] = __fadd_rn(zv, dd);
        lsum += (double)dd * (double)dd;
    }
    dred[tid] = lsum;
    __syncthreads();
#pragma unroll
    for (int s = 128; s > 0; s >>= 1) {
        if (tid < s) dred[tid] += dred[tid + s];
        __syncthreads();
    }
    if (tid == 0) partials[blockIdx.x] = dred[0];
}

extern "C" void kernel_launch(void* const* d_in, const int* in_sizes, int n_in,
                              void* d_out, int out_size, void* d_ws, size_t ws_size,
                              hipStream_t stream) {
    (void)n_in; (void)out_size;
    const float* z = (const float*)d_in[0];
    const float* e = (const float*)d_in[1];
    if (in_sizes[0] == NE * EDIM) { const float* t = z; z = e; e = t; }
    float* out      = (float*)d_out;
    float* out_zq   = out;
    float* out_loss = out + (size_t)NROWS * EDIM;
    float* out_idx  = out_loss + 1;

    char* ws = (char*)d_ws;
    float*  z2g      = (float*)(ws + WS_Z2);
    float*  e2f      = (float*)(ws + WS_E2);
    double* partials = (double*)(ws + WS_PART);

    rownorm_kernel<<<(NE + 255) / 256, 256, 0, stream>>>(e, e2f, NE);

    if (ws_size >= WS_END) {
        int* cnt  = (int*)(ws + WS_CNT);
        int* list = (int*)(ws + WS_LIST);
        int* ci1  = (int*)(ws + WS_CI1);
        int* ci2  = (int*)(ws + WS_CI2);
        int* flg  = (int*)(ws + WS_FLG);
        u16* Bp   = (u16*)(ws + WS_BP);
        u16* zhi  = (u16*)d_out;                       // zq region as scratch
        u16* zlo  = zhi + (size_t)NROWS * EDIM;

        hipMemsetAsync(cnt, 0, 4, stream);
        rownorm_split_kernel<<<NROWS / 16, 256, 0, stream>>>(z, z2g, zhi, zlo);
        build_b_kernel<<<NE * EDIM / 256, 256, 0, stream>>>(e, Bp);
        vq_mfma_kernel<<<NROWS / 128, 256, 0, stream>>>(zhi, zlo, Bp, e2f, ci1, ci2, flg);
        vq_refine_kernel<<<NROWS / 64, 256, 0, stream>>>(z, e, z2g, e2f, ci1, ci2, flg,
                                                         out_idx, list, cnt, out_zq, partials);
        vq_fallback_kernel<<<512, 256, 0, stream>>>(z, e, z2g, e2f, list, cnt,
                                                    out_idx, out_zq, partials + 2048);
        vq_loss_kernel<<<1, 256, 0, stream>>>(partials, 2560, out_loss);
    } else {
        rownorm_kernel<<<NROWS / 256, 256, 0, stream>>>(z, z2g, NROWS);
        vq_main_r3<<<NROWS / BM, 256, 0, stream>>>(z, e, z2g, e2f, out_zq, out_idx, partials);
        vq_loss_kernel<<<1, 256, 0, stream>>>(partials, 1024, out_loss);
    }
}

// Round 19
// 551.860 us; speedup vs baseline: 1.2905x; 1.0407x over previous
//
#include <hip/hip_runtime.h>
#include <cfloat>

#define NROWS 131072
#define EDIM 256
#define NE 1024
#define DELTA 2.0e-4f

#define BM 128
#define BN 128
#define BK 32

typedef unsigned short u16;
typedef __attribute__((ext_vector_type(8))) short bf16x8;
typedef __attribute__((ext_vector_type(4))) float f32x4;

// ---- ws layout (bytes) ----
#define WS_Z2    0u
#define WS_E2    524288u
#define WS_PART  528384u        // 2560 doubles (2048 refine + 512 fallback)
#define WS_CNT   548864u
#define WS_LIST  549120u
#define WS_CI1   1073408u
#define WS_CI2   1597696u
#define WS_FLG   2121984u
#define WS_BP    2646272u
#define WS_END   4219136u

// ---------- numpy pairwise sum-of-squares (256 elems), serial form ----------
__device__ __forceinline__ float np_sumsq256(const float* __restrict__ row) {
    float s[2];
#pragma unroll
    for (int h = 0; h < 2; ++h) {
        const float* a = row + h * 128;
        float r[8];
#pragma unroll
        for (int j = 0; j < 8; ++j) r[j] = __fmul_rn(a[j], a[j]);
        for (int i = 8; i < 128; i += 8) {
#pragma unroll
            for (int j = 0; j < 8; ++j)
                r[j] = __fadd_rn(r[j], __fmul_rn(a[i + j], a[i + j]));
        }
        s[h] = __fadd_rn(__fadd_rn(__fadd_rn(r[0], r[1]), __fadd_rn(r[2], r[3])),
                         __fadd_rn(__fadd_rn(r[4], r[5]), __fadd_rn(r[6], r[7])));
    }
    return __fadd_rn(s[0], s[1]);
}

__device__ __forceinline__ u16 bf16_rn(float x) {
    unsigned u = __float_as_uint(x);
    return (u16)((u + 0x7fffu + ((u >> 16) & 1u)) >> 16);
}

// ---------- fused, COALESCED: z2 (numpy-pairwise via shfl tree) + z->zhi/zlo ----------
__global__ __launch_bounds__(256)
void rownorm_split_kernel(const float* __restrict__ z, float* __restrict__ z2out,
                          u16* __restrict__ zhi, u16* __restrict__ zlo) {
    __shared__ float zl[16 * 256];   // 16 KiB
    const int tid = threadIdx.x;
    const size_t base4 = (size_t)blockIdx.x * 1024;   // float4 index of block base

    {
        const float4* src = reinterpret_cast<const float4*>(z) + base4;
        float4* dst = reinterpret_cast<float4*>(zl);
#pragma unroll
        for (int i = 0; i < 4; ++i) dst[tid + 256 * i] = src[tid + 256 * i];
    }
    __syncthreads();

    {
        const int row = tid >> 4;
        const int j16 = tid & 15;
        const int h = j16 >> 3, j = j16 & 7;
        const float* a = &zl[row * 256 + h * 128];
        float r = __fmul_rn(a[j], a[j]);
#pragma unroll
        for (int i = 8; i < 128; i += 8)
            r = __fadd_rn(r, __fmul_rn(a[i + j], a[i + j]));
        r = __fadd_rn(r, __shfl_xor(r, 1));
        r = __fadd_rn(r, __shfl_xor(r, 2));
        r = __fadd_rn(r, __shfl_xor(r, 4));   // = s[h]
        r = __fadd_rn(r, __shfl_xor(r, 8));   // = s[0]+s[1]
        if (j16 == 0) z2out[blockIdx.x * 16 + row] = r;
    }

    {
        ushort4* ph = reinterpret_cast<ushort4*>(zhi) + base4;
        ushort4* pl = reinterpret_cast<ushort4*>(zlo) + base4;
        const float4* sp = reinterpret_cast<const float4*>(zl);
#pragma unroll
        for (int i = 0; i < 4; ++i) {
            const int q = tid + 256 * i;
            float4 v = sp[q];
            float xs[4] = {v.x, v.y, v.z, v.w};
            u16 hh[4], lo[4];
#pragma unroll
            for (int c = 0; c < 4; ++c) {
                u16 hv = bf16_rn(xs[c]);
                float hf = __uint_as_float(((unsigned)hv) << 16);
                hh[c] = hv;
                lo[c] = bf16_rn(__fsub_rn(xs[c], hf));
            }
            ph[q] = make_ushort4(hh[0], hh[1], hh[2], hh[3]);
            pl[q] = make_ushort4(lo[0], lo[1], lo[2], lo[3]);
        }
    }
}

__global__ __launch_bounds__(256)
void rownorm_kernel(const float* __restrict__ x, float* __restrict__ out, int nrows) {
    int row = blockIdx.x * blockDim.x + threadIdx.x;
    if (row < nrows) out[row] = np_sumsq256(x + (size_t)row * EDIM);
}

// B' layout: [e_hi | e_lo], stride 512 per code row
__global__ __launch_bounds__(256)
void build_b_kernel(const float* __restrict__ e, u16* __restrict__ Bp) {
    int idx = blockIdx.x * 256 + threadIdx.x;
    int row = idx >> 8, k = idx & 255;
    float x = e[idx];
    u16 hh = bf16_rn(x);
    float hf = __uint_as_float(((unsigned)hh) << 16);
    u16 lo = bf16_rn(__fsub_rn(x, hf));
    Bp[row * 512 + k] = hh;
    Bp[row * 512 + 256 + k] = lo;
}

__device__ __forceinline__ void gload_lds16(const void* g, void* lds) {
    __builtin_amdgcn_global_load_lds((const __attribute__((address_space(1))) void*)g,
                                     (__attribute__((address_space(3))) void*)lds,
                                     16, 0, 0);
}

#define LEXLT(va, ia, vb, ib) ((va) < (vb) || ((va) == (vb) && (ia) < (ib)))

#define MERGE5(a1, ai1, a2, ai2, a3, b1, bi1, b2, bi2, b3)                    \
    {                                                                         \
        float n1v, n2v, n3v; int n1i, n2i;                                    \
        if (LEXLT(a1, ai1, b1, bi1)) {                                        \
            n1v = a1; n1i = ai1;                                              \
            if (LEXLT(a2, ai2, b1, bi1)) { n2v = a2; n2i = ai2; n3v = fminf(a3, b1); } \
            else                          { n2v = b1; n2i = bi1; n3v = fminf(a2, b2); } \
        } else {                                                              \
            n1v = b1; n1i = bi1;                                              \
            if (LEXLT(b2, bi2, a1, ai1)) { n2v = b2; n2i = bi2; n3v = fminf(b3, a1); } \
            else                          { n2v = a1; n2i = ai1; n3v = fminf(b2, a2); } \
        }                                                                     \
        a1 = n1v; ai1 = n1i; a2 = n2v; ai2 = n2i; a3 = n3v;                   \
    }

#define WAITVM(N) asm volatile("s_waitcnt vmcnt(" #N ")" ::: "memory")
#define RBAR()    asm volatile("s_barrier" ::: "memory")

// ---------- K2: bf16 MFMA, D[code][z-row], tile 128z x 256codes, fr4 x fc4,
//            32-col chunks, double-buffered, counted-vmcnt 3-step pipeline ----------
// 512 thr / 8 waves (wrg 0..1 z-groups x wcg 0..3 code-groups).
// LDS 60 KiB + VGPR ~104 -> 2 blocks/CU at runtime (cross-block TLP hides
// per-step barrier/drain latency). Per (nc, j): S1 zhi x ehi, S2 zhi x elo,
// S3 zlo x ehi; stage counts 3/0/3; waits 3/1/3 -- never 0 mid-loop.
__global__ __launch_bounds__(512, 2)
void vq_mfma_kernel(const u16* __restrict__ zhi, const u16* __restrict__ zlo,
                    const u16* __restrict__ Bp, const float* __restrict__ e2f,
                    int* __restrict__ ci1, int* __restrict__ ci2, int* __restrict__ cflag) {
    __shared__ __align__(16) u16  At[2][128 * 32];  // 2 x 8 KiB  (z col-chunk)
    __shared__ __align__(16) u16  Bt[2][256 * 32];  // 2 x 16 KiB (codes col-chunk)
    __shared__ float e2s[1024];                     // 4 KiB
    __shared__ float mrg[128 * 4 * 4];              // 8 KiB [row][wcg][v1,v2,v3,pk]

    const int tid = threadIdx.x;
    const int m0  = blockIdx.x * 128;
    const int l   = tid & 63;
    const int wid = tid >> 6;
    const int wrg = wid >> 2;       // 0..1 -> z-rows wrg*64
    const int wcg = wid & 3;        // 0..3 -> codes wcg*64 (within 256-chunk)
    const int lr  = l & 15;
    const int lg  = l >> 4;         // 0..3
    const int key = lr & 3;         // 4 chunks of 16B per 32-col row

    e2s[tid] = e2f[tid];
    e2s[tid + 512] = e2f[tid + 512];

    // staging map (32-col chunk): chunk c = tid (A) or s*512+tid (B);
    // row = c>>2, phys 16B slot = c&3; logical chunk at slot = (c&3)^(row&3)
    const int rsub = tid >> 2;                   // 0..127
    const int l4   = (tid & 3) ^ (rsub & 3);

#define SAT(BUF, SRC, COLC)                                                   \
    gload_lds16((SRC) + (size_t)(m0 + rsub) * 256 + (COLC) + l4 * 8,          \
                At[BUF] + (size_t)tid * 8);
#define SBT(BUF, NB, OFF)                                                     \
    {                                                                         \
        _Pragma("unroll")                                                     \
        for (int s = 0; s < 2; ++s)                                           \
            gload_lds16(Bp + (size_t)((NB) + s * 128 + rsub) * 512 + (OFF) + l4 * 8, \
                        Bt[BUF] + (size_t)(s * 512 + tid) * 8);               \
    }
#define MSTEP(RA, RB)                                                         \
    {                                                                         \
        const u16* Eb = Bt[RB] + (wcg * 64 + lr) * 32 + ((lg ^ key) * 8);     \
        const u16* Zb = At[RA] + (wrg * 64 + lr) * 32 + ((lg ^ key) * 8);     \
        bf16x8 a[4], b[4];                                                    \
        _Pragma("unroll")                                                     \
        for (int fr = 0; fr < 4; ++fr)                                        \
            a[fr] = *reinterpret_cast<const bf16x8*>(Eb + fr * 512);          \
        _Pragma("unroll")                                                     \
        for (int fc = 0; fc < 4; ++fc)                                        \
            b[fc] = *reinterpret_cast<const bf16x8*>(Zb + fc * 512);          \
        _Pragma("unroll")                                                     \
        for (int fr = 0; fr < 4; ++fr)                                        \
            _Pragma("unroll")                                                 \
            for (int fc = 0; fc < 4; ++fc)                                    \
                acc[fr][fc] = __builtin_amdgcn_mfma_f32_16x16x32_bf16(        \
                    a[fr], b[fc], acc[fr][fc], 0, 0, 0);                      \
    }

    // persistent per-lane top-3 state: slot = fc (z-row = wrg*64 + fc*16 + lr)
    float v1[4], v2[4], v3[4];
    unsigned pidx[4];
#pragma unroll
    for (int s = 0; s < 4; ++s) { v1[s] = FLT_MAX; v2[s] = FLT_MAX; v3[s] = FLT_MAX; pidx[s] = 0; }

    f32x4 acc[4][4];                       // [fr=code frag][fc=z frag]

    // ---- prologue: zhi chunk0 -> A0 [1], ehi(nc=0) chunk0 -> B0 [2] ----
    SAT(0, zhi, 0);
    SBT(0, 0, 0);
    WAITVM(0);
    RBAR();

#pragma unroll 1
    for (int nc = 0; nc < 4; ++nc) {           // code chunks of 256
        const int n0 = nc * 256;
#pragma unroll
        for (int fr = 0; fr < 4; ++fr)
#pragma unroll
            for (int fc = 0; fc < 4; ++fc) acc[fr][fc] = (f32x4){0.f, 0.f, 0.f, 0.f};

#pragma unroll 2
        for (int j = 0; j < 8; ++j) {
            const int xB = j & 1;
            const int c  = j * 32;
            // S1: zhi_j x ehi_j. Stage elo_j -> B(x^1) [2], zlo_j -> A1 [1].
            // In-flight: 3 old (zhi_j, ehi_j x2) + 3 new; WAITVM(3) drains the old.
            SBT(xB ^ 1, n0, 256 + c);
            SAT(1, zlo, c);
            WAITVM(3); RBAR(); MSTEP(0, xB); RBAR();
            // S2: zhi_j x elo_j. WAITVM(1) drains elo x2, leaves zlo.
            WAITVM(1); RBAR(); MSTEP(0, xB ^ 1); RBAR();
            // S3: zlo_j x ehi_j. Stage zhi_next -> A0 [1], ehi_next -> B(x^1) [2];
            // WAITVM(3) drains zlo, leaves the 3 new.
            if (j < 7) {
                SAT(0, zhi, c + 32);
                SBT(xB ^ 1, n0, c + 32);
                WAITVM(3);
            } else if (nc < 3) {
                SAT(0, zhi, 0);
                SBT(xB ^ 1, n0 + 256, 0);
                WAITVM(3);
            } else {
                WAITVM(0);
            }
            RBAR(); MSTEP(1, xB); RBAR();
        }

        // ---- register-local scan (overlaps next-nc in-flight loads) ----
#pragma unroll
        for (int fr = 0; fr < 4; ++fr) {
            const int cbase = n0 + wcg * 64 + fr * 16 + lg * 4;
            const float4 e2v = *reinterpret_cast<const float4*>(&e2s[cbase]);
#pragma unroll
            for (int q = 0; q < 4; ++q) {
                const unsigned n = (unsigned)(cbase + q);
                const float e2q = (q == 0) ? e2v.x : (q == 1) ? e2v.y : (q == 2) ? e2v.z : e2v.w;
#pragma unroll
                for (int fc = 0; fc < 4; ++fc) {
                    float d = __fmaf_rn(-2.0f, acc[fr][fc][q], e2q);
                    bool lt1 = d < v1[fc];
                    bool lt2 = d < v2[fc];
                    bool lt3 = d < v3[fc];
                    v3[fc] = lt2 ? v2[fc] : (lt3 ? d : v3[fc]);
                    v2[fc] = lt1 ? v1[fc] : (lt2 ? d : v2[fc]);
                    pidx[fc] = lt1 ? ((pidx[fc] << 16) | n)
                                   : (lt2 ? ((pidx[fc] & 0xffffu) | (n << 16)) : pidx[fc]);
                    v1[fc] = lt1 ? d : v1[fc];
                }
            }
        }
    }

    // ---- ONE butterfly per slot across lg groups (masks 16, 32) ----
#pragma unroll
    for (int s = 0; s < 4; ++s) {
        float a1 = v1[s], a2 = v2[s], a3 = v3[s];
        int ai1 = (int)(pidx[s] & 0xffffu), ai2 = (int)(pidx[s] >> 16);
#pragma unroll
        for (int m = 16; m <= 32; m <<= 1) {
            float b1 = __shfl_xor(a1, m), b2 = __shfl_xor(a2, m), b3 = __shfl_xor(a3, m);
            int bi1 = __shfl_xor(ai1, m), bi2 = __shfl_xor(ai2, m);
            MERGE5(a1, ai1, a2, ai2, a3, b1, bi1, b2, bi2, b3);
        }
        if (lg == 0) {
            int row = wrg * 64 + s * 16 + lr;
            float* p = &mrg[(row * 4 + wcg) * 4];
            p[0] = a1; p[1] = a2; p[2] = a3;
            p[3] = __uint_as_float(((unsigned)ai1 & 0xffffu) | ((unsigned)ai2 << 16));
        }
    }
    __syncthreads();

    if (tid < 128) {
        const float* p0 = &mrg[(tid * 4 + 0) * 4];
        float A1 = p0[0], A2 = p0[1], A3 = p0[2];
        unsigned pk = __float_as_uint(p0[3]);
        int I1 = (int)(pk & 0xffffu), I2 = (int)(pk >> 16);
#pragma unroll
        for (int w = 1; w < 4; ++w) {
            const float* p = &mrg[(tid * 4 + w) * 4];
            float b1 = p[0], b2 = p[1], b3 = p[2];
            unsigned q = __float_as_uint(p[3]);
            int bi1 = (int)(q & 0xffffu), bi2 = (int)(q >> 16);
            MERGE5(A1, I1, A2, I2, A3, b1, bi1, b2, bi2, b3);
        }
        ci1[m0 + tid] = I1;
        ci2[m0 + tid] = I2;
        cflag[m0 + tid] = (A3 - A1 <= DELTA) ? 1 : 0;
    }
}

// ---------- exact fp32 distance (verified r3 chain) ----------
__device__ __forceinline__ float exact_g(const float* __restrict__ zr,
                                         const float* __restrict__ er,
                                         float z2v, float e2v) {
    float m = 0.f;
    for (int k = 0; k < 256; k += 4) {
        float4 zv = *reinterpret_cast<const float4*>(zr + k);
        float4 ev = *reinterpret_cast<const float4*>(er + k);
        m = __fmaf_rn(zv.x, ev.x, m);
        m = __fmaf_rn(zv.y, ev.y, m);
        m = __fmaf_rn(zv.z, ev.z, m);
        m = __fmaf_rn(zv.w, ev.w, m);
    }
    return __fsub_rn(__fadd_rn(z2v, e2v), __fmul_rn(2.0f, m));
}

// ---------- K3: exact top-2 refine + zq/loss for unflagged rows ----------
__global__ __launch_bounds__(256)
void vq_refine_kernel(const float* __restrict__ z, const float* __restrict__ e,
                      const float* __restrict__ z2g, const float* __restrict__ e2f,
                      const int* __restrict__ ci1, const int* __restrict__ ci2,
                      const int* __restrict__ cflag,
                      float* __restrict__ out_idx, int* __restrict__ list,
                      int* __restrict__ counter,
                      float* __restrict__ out_zq, double* __restrict__ partials) {
    __shared__ float  gbuf[128];
    __shared__ int    fIdx[64];
    __shared__ int    fFlag[64];
    __shared__ double dred[256];
    const int tid = threadIdx.x;
    const int r0  = blockIdx.x * 64;

    if (tid < 128) {
        int r = tid >> 1, which = tid & 1;
        int row = r0 + r;
        int c = which ? ci2[row] : ci1[row];
        gbuf[tid] = exact_g(z + (size_t)row * EDIM, e + (size_t)c * EDIM, z2g[row], e2f[c]);
    }
    __syncthreads();
    if (tid < 64) {
        int row = r0 + tid;
        int a = ci1[row], b = ci2[row];
        float ga = gbuf[tid * 2], gb = gbuf[tid * 2 + 1];
        int fi = (gb < ga || (gb == ga && b < a)) ? b : a;
        fIdx[tid] = fi;
        int fl = cflag[row];
        fFlag[tid] = fl;
        out_idx[row] = (float)fi;
        if (fl) { int p = atomicAdd(counter, 1); list[p] = row; }
    }
    __syncthreads();

    double lsum = 0.0;
    for (int r = 0; r < 64; ++r) {
        if (!fFlag[r]) {
            int row = r0 + r;
            float zv = z[(size_t)row * EDIM + tid];
            float ev = e[(size_t)fIdx[r] * EDIM + tid];
            float dd = __fsub_rn(ev, zv);
            out_zq[(size_t)row * EDIM + tid] = __fadd_rn(zv, dd);
            lsum += (double)dd * (double)dd;
        }
    }
    dred[tid] = lsum;
    __syncthreads();
#pragma unroll
    for (int s = 128; s > 0; s >>= 1) {
        if (tid < s) dred[tid] += dred[tid + s];
        __syncthreads();
    }
    if (tid == 0) partials[blockIdx.x] = dred[0];
}

// ---------- K3b: full exact rescan for flagged rows ----------
__global__ __launch_bounds__(256)
void vq_fallback_kernel(const float* __restrict__ z, const float* __restrict__ e,
                        const float* __restrict__ z2g, const float* __restrict__ e2f,
                        const int* __restrict__ list, const int* __restrict__ counter,
                        float* __restrict__ out_idx, float* __restrict__ out_zq,
                        double* __restrict__ partials2) {
    __shared__ float  elds[64 * 257];
    __shared__ float  zlds[4][256];
    __shared__ float  z2s[4];
    __shared__ double dred[256];
    const int n   = *counter;
    const int tid = threadIdx.x;
    const int w   = tid >> 6;
    const int lane = tid & 63;
    double lsum = 0.0;

    for (int base = blockIdx.x * 4; base < n; base += gridDim.x * 4) {
        const int nr = min(4, n - base);
        __syncthreads();
        for (int i = tid; i < nr * 256; i += 256)
            zlds[i >> 8][i & 255] = z[(size_t)list[base + (i >> 8)] * EDIM + (i & 255)];
        if (tid < nr) z2s[tid] = z2g[list[base + tid]];

        float bv = FLT_MAX; int bi = 0x7fffffff;
        const int srow  = ((tid >> 4) & 3);
        const int scolq = (tid & 15) | ((tid >> 6) << 4);
        for (int c0 = 0; c0 < NE; c0 += 64) {
            __syncthreads();
#pragma unroll
            for (int s = 0; s < 16; ++s) {
                int row = 4 * s + srow;
                float4 v = *reinterpret_cast<const float4*>(e + (size_t)(c0 + row) * EDIM + scolq * 4);
                float* d = &elds[row * 257 + scolq * 4];
                d[0] = v.x; d[1] = v.y; d[2] = v.z; d[3] = v.w;
            }
            __syncthreads();
            const int code = c0 + lane;
            const float* er = &elds[lane * 257];
            const float* zr = zlds[w];
            float m = 0.f;
#pragma unroll 8
            for (int k = 0; k < 256; ++k)
                m = __fmaf_rn(zr[k], er[k], m);
            float g = __fsub_rn(__fadd_rn(z2s[w], e2f[code]), __fmul_rn(2.0f, m));
            if (g < bv || (g == bv && code < bi)) { bv = g; bi = code; }
        }
#pragma unroll
        for (int m2 = 1; m2 < 64; m2 <<= 1) {
            float ov = __shfl_xor(bv, m2); int oi = __shfl_xor(bi, m2);
            if (ov < bv || (ov == bv && oi < bi)) { bv = ov; bi = oi; }
        }
        if (w < nr) {
            int row = list[base + w];
            if (lane == 0) out_idx[row] = (float)bi;
            const float* er2 = e + (size_t)bi * EDIM;
            for (int c = lane; c < 256; c += 64) {
                float zv = zlds[w][c];
                float dd = __fsub_rn(er2[c], zv);
                out_zq[(size_t)row * EDIM + c] = __fadd_rn(zv, dd);
                lsum += (double)dd * (double)dd;
            }
        }
    }
    dred[tid] = lsum;
    __syncthreads();
#pragma unroll
    for (int s = 128; s > 0; s >>= 1) {
        if (tid < s) dred[tid] += dred[tid + s];
        __syncthreads();
    }
    if (tid == 0) partials2[blockIdx.x] = dred[0];
}

__global__ void vq_loss_kernel(const double* __restrict__ partials, int count,
                               float* __restrict__ out_loss) {
    __shared__ double s[256];
    const int tid = threadIdx.x;
    double v = 0.0;
    for (int i = tid; i < count; i += 256) v += partials[i];
    s[tid] = v;
    __syncthreads();
    for (int k = 128; k > 0; k >>= 1) {
        if (tid < k) s[tid] += s[tid + k];
        __syncthreads();
    }
    if (tid == 0) {
        double mean = s[0] / ((double)NROWS * (double)EDIM);
        out_loss[0] = (float)(1.25 * mean);
    }
}

// ================= fallback (proven r3 pipeline) if ws too small =================
__global__ __launch_bounds__(256, 2)
void vq_main_r3(const float* __restrict__ z, const float* __restrict__ e,
                const float* __restrict__ z2g, const float* __restrict__ e2g,
                float* __restrict__ out_zq, float* __restrict__ out_idx,
                double* __restrict__ partials) {
    __shared__ float A[BK][BM];
    __shared__ float Bm[BK][BN];
    __shared__ float e2s[BN];
    __shared__ int   fIdx[BM];
    __shared__ double dred[256];
    const int tid = threadIdx.x;
    const int m0 = blockIdx.x * BM;
    const int trow = tid >> 4, tcol = tid & 15;
    float z2r[8];
#pragma unroll
    for (int i = 0; i < 8; ++i) z2r[i] = z2g[m0 + trow * 8 + i];
    float bestV[8]; int bestI[8];
#pragma unroll
    for (int i = 0; i < 8; ++i) { bestV[i] = FLT_MAX; bestI[i] = 0; }
    for (int n0 = 0; n0 < NE; n0 += BN) {
        float acc[8][8];
#pragma unroll
        for (int i = 0; i < 8; ++i)
#pragma unroll
            for (int j = 0; j < 8; ++j) acc[i][j] = 0.f;
        __syncthreads();
        if (tid < BN) e2s[tid] = e2g[n0 + tid];
        for (int k0 = 0; k0 < EDIM; k0 += BK) {
            __syncthreads();
#pragma unroll
            for (int s = 0; s < 4; ++s) {
                int q = tid + 256 * s, row = q >> 3, kc = (q & 7) << 2;
                float4 va = *reinterpret_cast<const float4*>(z + (size_t)(m0 + row) * EDIM + k0 + kc);
                A[kc + 0][row] = va.x; A[kc + 1][row] = va.y; A[kc + 2][row] = va.z; A[kc + 3][row] = va.w;
                float4 vb = *reinterpret_cast<const float4*>(e + (size_t)(n0 + row) * EDIM + k0 + kc);
                Bm[kc + 0][row] = vb.x; Bm[kc + 1][row] = vb.y; Bm[kc + 2][row] = vb.z; Bm[kc + 3][row] = vb.w;
            }
            __syncthreads();
#pragma unroll
            for (int k = 0; k < BK; ++k) {
                float a[8], b[8];
                *reinterpret_cast<float4*>(&a[0]) = *reinterpret_cast<const float4*>(&A[k][trow * 8]);
                *reinterpret_cast<float4*>(&a[4]) = *reinterpret_cast<const float4*>(&A[k][trow * 8 + 4]);
                *reinterpret_cast<float4*>(&b[0]) = *reinterpret_cast<const float4*>(&Bm[k][tcol * 8]);
                *reinterpret_cast<float4*>(&b[4]) = *reinterpret_cast<const float4*>(&Bm[k][tcol * 8 + 4]);
#pragma unroll
                for (int i = 0; i < 8; ++i)
#pragma unroll
                    for (int j = 0; j < 8; ++j) acc[i][j] = __fmaf_rn(a[i], b[j], acc[i][j]);
            }
        }
#pragma unroll
        for (int i = 0; i < 8; ++i)
#pragma unroll
            for (int j = 0; j < 8; ++j) {
                int n = n0 + tcol * 8 + j;
                float d = __fsub_rn(__fadd_rn(z2r[i], e2s[tcol * 8 + j]), __fmul_rn(2.0f, acc[i][j]));
                if (d < bestV[i]) { bestV[i] = d; bestI[i] = n; }
            }
    }
    __syncthreads();
    float* red_v = &A[0][0];
    int* red_i = reinterpret_cast<int*>(&Bm[0][0]);
#pragma unroll
    for (int i = 0; i < 8; ++i) {
        int row = trow * 8 + i;
        red_v[row * 16 + tcol] = bestV[i];
        red_i[row * 16 + tcol] = bestI[i];
    }
    __syncthreads();
    if (tid < BM) {
        float b1 = FLT_MAX; int i1 = 0x7fffffff;
        for (int t = 0; t < 16; ++t) {
            float v = red_v[tid * 16 + t]; int id = red_i[tid * 16 + t];
            if (v < b1 || (v == b1 && id < i1)) { b1 = v; i1 = id; }
        }
        fIdx[tid] = i1;
        out_idx[m0 + tid] = (float)i1;
    }
    __syncthreads();
    double lsum = 0.0;
    for (int r = 0; r < BM; ++r) {
        int fi = fIdx[r];
        float zv = z[(size_t)(m0 + r) * EDIM + tid];
        float ev = e[(size_t)fi * EDIM + tid];
        float dd = __fsub_rn(ev, zv);
        out_zq[(size_t)(m0 + r) * EDIM + tid] = __fadd_rn(zv, dd);
        lsum += (double)dd * (double)dd;
    }
    dred[tid] = lsum;
    __syncthreads();
#pragma unroll
    for (int s = 128; s > 0; s >>= 1) {
        if (tid < s) dred[tid] += dred[tid + s];
        __syncthreads();
    }
    if (tid == 0) partials[blockIdx.x] = dred[0];
}

extern "C" void kernel_launch(void* const* d_in, const int* in_sizes, int n_in,
                              void* d_out, int out_size, void* d_ws, size_t ws_size,
                              hipStream_t stream) {
    (void)n_in; (void)out_size;
    const float* z = (const float*)d_in[0];
    const float* e = (const float*)d_in[1];
    if (in_sizes[0] == NE * EDIM) { const float* t = z; z = e; e = t; }
    float* out      = (float*)d_out;
    float* out_zq   = out;
    float* out_loss = out + (size_t)NROWS * EDIM;
    float* out_idx  = out_loss + 1;

    char* ws = (char*)d_ws;
    float*  z2g      = (float*)(ws + WS_Z2);
    float*  e2f      = (float*)(ws + WS_E2);
    double* partials = (double*)(ws + WS_PART);

    rownorm_kernel<<<(NE + 255) / 256, 256, 0, stream>>>(e, e2f, NE);

    if (ws_size >= WS_END) {
        int* cnt  = (int*)(ws + WS_CNT);
        int* list = (int*)(ws + WS_LIST);
        int* ci1  = (int*)(ws + WS_CI1);
        int* ci2  = (int*)(ws + WS_CI2);
        int* flg  = (int*)(ws + WS_FLG);
        u16* Bp   = (u16*)(ws + WS_BP);
        u16* zhi  = (u16*)d_out;                       // zq region as scratch
        u16* zlo  = zhi + (size_t)NROWS * EDIM;

        hipMemsetAsync(cnt, 0, 4, stream);
        rownorm_split_kernel<<<NROWS / 16, 256, 0, stream>>>(z, z2g, zhi, zlo);
        build_b_kernel<<<NE * EDIM / 256, 256, 0, stream>>>(e, Bp);
        vq_mfma_kernel<<<NROWS / 128, 512, 0, stream>>>(zhi, zlo, Bp, e2f, ci1, ci2, flg);
        vq_refine_kernel<<<NROWS / 64, 256, 0, stream>>>(z, e, z2g, e2f, ci1, ci2, flg,
                                                         out_idx, list, cnt, out_zq, partials);
        vq_fallback_kernel<<<512, 256, 0, stream>>>(z, e, z2g, e2f, list, cnt,
                                                    out_idx, out_zq, partials + 2048);
        vq_loss_kernel<<<1, 256, 0, stream>>>(partials, 2560, out_loss);
    } else {
        rownorm_kernel<<<NROWS / 256, 256, 0, stream>>>(z, z2g, NROWS);
        vq_main_r3<<<NROWS / BM, 256, 0, stream>>>(z, e, z2g, e2f, out_zq, out_idx, partials);
        vq_loss_kernel<<<1, 256, 0, stream>>>(partials, 1024, out_loss);
    }
}

// Round 20
// 509.000 us; speedup vs baseline: 1.3992x; 1.0842x over previous
//
#include <hip/hip_runtime.h>
#include <cfloat>

#define NROWS 131072
#define EDIM 256
#define NE 1024
#define DELTA 2.0e-4f

#define BM 128
#define BN 128
#define BK 32

typedef unsigned short u16;
typedef __attribute__((ext_vector_type(8))) short bf16x8;
typedef __attribute__((ext_vector_type(4))) float f32x4;

// ---- ws layout (bytes) ----
#define WS_Z2    0u
#define WS_E2    524288u
#define WS_PART  528384u        // 2560 doubles (2048 refine + 512 fallback)
#define WS_CNT   548864u
#define WS_LIST  549120u
#define WS_CI1   1073408u
#define WS_CI2   1597696u
#define WS_FLG   2121984u
#define WS_BP    2646272u
#define WS_END   4219136u

// ---------- numpy pairwise sum-of-squares (256 elems), serial form ----------
__device__ __forceinline__ float np_sumsq256(const float* __restrict__ row) {
    float s[2];
#pragma unroll
    for (int h = 0; h < 2; ++h) {
        const float* a = row + h * 128;
        float r[8];
#pragma unroll
        for (int j = 0; j < 8; ++j) r[j] = __fmul_rn(a[j], a[j]);
        for (int i = 8; i < 128; i += 8) {
#pragma unroll
            for (int j = 0; j < 8; ++j)
                r[j] = __fadd_rn(r[j], __fmul_rn(a[i + j], a[i + j]));
        }
        s[h] = __fadd_rn(__fadd_rn(__fadd_rn(r[0], r[1]), __fadd_rn(r[2], r[3])),
                         __fadd_rn(__fadd_rn(r[4], r[5]), __fadd_rn(r[6], r[7])));
    }
    return __fadd_rn(s[0], s[1]);
}

__device__ __forceinline__ u16 bf16_rn(float x) {
    unsigned u = __float_as_uint(x);
    return (u16)((u + 0x7fffu + ((u >> 16) & 1u)) >> 16);
}

// ---------- fused, COALESCED: z2 (numpy-pairwise via shfl tree) + z->zhi/zlo ----------
__global__ __launch_bounds__(256)
void rownorm_split_kernel(const float* __restrict__ z, float* __restrict__ z2out,
                          u16* __restrict__ zhi, u16* __restrict__ zlo) {
    __shared__ float zl[16 * 256];   // 16 KiB
    const int tid = threadIdx.x;
    const size_t base4 = (size_t)blockIdx.x * 1024;   // float4 index of block base

    {
        const float4* src = reinterpret_cast<const float4*>(z) + base4;
        float4* dst = reinterpret_cast<float4*>(zl);
#pragma unroll
        for (int i = 0; i < 4; ++i) dst[tid + 256 * i] = src[tid + 256 * i];
    }
    __syncthreads();

    {
        const int row = tid >> 4;
        const int j16 = tid & 15;
        const int h = j16 >> 3, j = j16 & 7;
        const float* a = &zl[row * 256 + h * 128];
        float r = __fmul_rn(a[j], a[j]);
#pragma unroll
        for (int i = 8; i < 128; i += 8)
            r = __fadd_rn(r, __fmul_rn(a[i + j], a[i + j]));
        r = __fadd_rn(r, __shfl_xor(r, 1));
        r = __fadd_rn(r, __shfl_xor(r, 2));
        r = __fadd_rn(r, __shfl_xor(r, 4));   // = s[h]
        r = __fadd_rn(r, __shfl_xor(r, 8));   // = s[0]+s[1]
        if (j16 == 0) z2out[blockIdx.x * 16 + row] = r;
    }

    {
        ushort4* ph = reinterpret_cast<ushort4*>(zhi) + base4;
        ushort4* pl = reinterpret_cast<ushort4*>(zlo) + base4;
        const float4* sp = reinterpret_cast<const float4*>(zl);
#pragma unroll
        for (int i = 0; i < 4; ++i) {
            const int q = tid + 256 * i;
            float4 v = sp[q];
            float xs[4] = {v.x, v.y, v.z, v.w};
            u16 hh[4], lo[4];
#pragma unroll
            for (int c = 0; c < 4; ++c) {
                u16 hv = bf16_rn(xs[c]);
                float hf = __uint_as_float(((unsigned)hv) << 16);
                hh[c] = hv;
                lo[c] = bf16_rn(__fsub_rn(xs[c], hf));
            }
            ph[q] = make_ushort4(hh[0], hh[1], hh[2], hh[3]);
            pl[q] = make_ushort4(lo[0], lo[1], lo[2], lo[3]);
        }
    }
}

__global__ __launch_bounds__(256)
void rownorm_kernel(const float* __restrict__ x, float* __restrict__ out, int nrows) {
    int row = blockIdx.x * blockDim.x + threadIdx.x;
    if (row < nrows) out[row] = np_sumsq256(x + (size_t)row * EDIM);
}

// B' layout: [e_hi | e_lo], stride 512 per code row
__global__ __launch_bounds__(256)
void build_b_kernel(const float* __restrict__ e, u16* __restrict__ Bp) {
    int idx = blockIdx.x * 256 + threadIdx.x;
    int row = idx >> 8, k = idx & 255;
    float x = e[idx];
    u16 hh = bf16_rn(x);
    float hf = __uint_as_float(((unsigned)hh) << 16);
    u16 lo = bf16_rn(__fsub_rn(x, hf));
    Bp[row * 512 + k] = hh;
    Bp[row * 512 + 256 + k] = lo;
}

__device__ __forceinline__ void gload_lds16(const void* g, void* lds) {
    __builtin_amdgcn_global_load_lds((const __attribute__((address_space(1))) void*)g,
                                     (__attribute__((address_space(3))) void*)lds,
                                     16, 0, 0);
}

#define LEXLT(va, ia, vb, ib) ((va) < (vb) || ((va) == (vb) && (ia) < (ib)))

#define MERGE5(a1, ai1, a2, ai2, a3, b1, bi1, b2, bi2, b3)                    \
    {                                                                         \
        float n1v, n2v, n3v; int n1i, n2i;                                    \
        if (LEXLT(a1, ai1, b1, bi1)) {                                        \
            n1v = a1; n1i = ai1;                                              \
            if (LEXLT(a2, ai2, b1, bi1)) { n2v = a2; n2i = ai2; n3v = fminf(a3, b1); } \
            else                          { n2v = b1; n2i = bi1; n3v = fminf(a2, b2); } \
        } else {                                                              \
            n1v = b1; n1i = bi1;                                              \
            if (LEXLT(b2, bi2, a1, ai1)) { n2v = b2; n2i = bi2; n3v = fminf(b3, a1); } \
            else                          { n2v = a1; n2i = ai1; n3v = fminf(b2, a2); } \
        }                                                                     \
        a1 = n1v; ai1 = n1i; a2 = n2v; ai2 = n2i; a3 = n3v;                   \
    }

#define WAITVM(N) asm volatile("s_waitcnt vmcnt(" #N ")" ::: "memory")
#define RBAR()    asm volatile("s_barrier" ::: "memory")

// ---------- K2 (r16-proven, 307us): bf16 MFMA, D[code][z-row], tile 128x256,
//            fr4 x fc4, 64-col chunks, double-buffered 12-step counted-vmcnt ----------
__global__ __launch_bounds__(512, 2)
void vq_mfma_kernel(const u16* __restrict__ zhi, const u16* __restrict__ zlo,
                    const u16* __restrict__ Bp, const float* __restrict__ e2f,
                    int* __restrict__ ci1, int* __restrict__ ci2, int* __restrict__ cflag) {
    __shared__ __align__(16) u16  At[2][128 * 64];  // 2 x 16 KiB (z)
    __shared__ __align__(16) u16  Bt[2][256 * 64];  // 2 x 32 KiB (codes)
    __shared__ float e2s[1024];                     // 4 KiB
    __shared__ float mrg[128 * 4 * 4];              // 8 KiB [row][wcg][v1,v2,v3,pk]

    const int tid = threadIdx.x;
    const int m0  = blockIdx.x * 128;
    const int l   = tid & 63;
    const int wid = tid >> 6;
    const int wrg = wid >> 2;       // 0..1 -> z-rows wrg*64
    const int wcg = wid & 3;        // 0..3 -> codes wcg*64 (within 256-chunk)
    const int lr  = l & 15;
    const int lg  = l >> 4;         // 0..3
    const int key = lr & 7;

    e2s[tid] = e2f[tid];
    e2s[tid + 512] = e2f[tid + 512];

    // staging map: chunk c = s*512+tid; row = s*64 + rsub; row&7 == rsub&7
    const int rsub = tid >> 3;                 // 0..63
    const int lch  = (tid & 7) ^ (rsub & 7);   // logical 16B chunk at this slot

#define SAT(BUF, SRC, COLC)                                                   \
    {                                                                         \
        _Pragma("unroll")                                                     \
        for (int s = 0; s < 2; ++s)                                           \
            gload_lds16((SRC) + (size_t)(m0 + s * 64 + rsub) * 256 + (COLC) + lch * 8, \
                        At[BUF] + (size_t)(s * 512 + tid) * 8);               \
    }
#define SBT(BUF, NB, OFF)                                                     \
    {                                                                         \
        _Pragma("unroll")                                                     \
        for (int s = 0; s < 4; ++s)                                           \
            gload_lds16(Bp + (size_t)((NB) + s * 64 + rsub) * 512 + (OFF) + lch * 8, \
                        Bt[BUF] + (size_t)(s * 512 + tid) * 8);               \
    }
#define MSTEP(RA, RB)                                                         \
    {                                                                         \
        const u16* Eb = Bt[RB] + (wcg * 64 + lr) * 64;                        \
        const u16* Zb = At[RA] + (wrg * 64 + lr) * 64;                        \
        _Pragma("unroll")                                                     \
        for (int kk = 0; kk < 2; ++kk) {                                      \
            const int go = ((kk * 4 + lg) ^ key) * 8;                         \
            bf16x8 a[4], b[4];                                                \
            _Pragma("unroll")                                                 \
            for (int fr = 0; fr < 4; ++fr)                                    \
                a[fr] = *reinterpret_cast<const bf16x8*>(Eb + fr * 1024 + go);\
            _Pragma("unroll")                                                 \
            for (int fc = 0; fc < 4; ++fc)                                    \
                b[fc] = *reinterpret_cast<const bf16x8*>(Zb + fc * 1024 + go);\
            _Pragma("unroll")                                                 \
            for (int fr = 0; fr < 4; ++fr)                                    \
                _Pragma("unroll")                                             \
                for (int fc = 0; fc < 4; ++fc)                                \
                    acc[fr][fc] = __builtin_amdgcn_mfma_f32_16x16x32_bf16(    \
                        a[fr], b[fc], acc[fr][fc], 0, 0, 0);                  \
        }                                                                     \
    }

    // persistent per-lane top-3 state: slot = fc (z-row = wrg*64 + fc*16 + lr)
    float v1[4], v2[4], v3[4];
    unsigned pidx[4];
#pragma unroll
    for (int s = 0; s < 4; ++s) { v1[s] = FLT_MAX; v2[s] = FLT_MAX; v3[s] = FLT_MAX; pidx[s] = 0; }

    f32x4 acc[4][4];                       // [fr=code frag][fc=z frag]

    // ---- prologue: stage (nc=0, k=0): A[0] = zhi col0, B[0] = ehi j0 ----
    SAT(0, zhi, 0);
    SBT(0, 0, 0);
    WAITVM(0);
    RBAR();

#pragma unroll 1
    for (int nc = 0; nc < 4; ++nc) {           // code chunks of 256
        const int n0 = nc * 256;
#pragma unroll
        for (int fr = 0; fr < 4; ++fr)
#pragma unroll
            for (int fc = 0; fc < 4; ++fc) acc[fr][fc] = (f32x4){0.f, 0.f, 0.f, 0.f};

        // 12-step schedule: step k stages step k+1's tiles into the other
        // buffers (A+B = 6 loads, B-only = 4), waits vmcnt(L_{k+1}) -- never 0.
        /* k0 */ SBT(1, n0, 256);                      WAITVM(4); RBAR(); MSTEP(0, 0); RBAR();
        /* k1 */ SAT(1, zhi, 64);  SBT(0, n0, 64);     WAITVM(6); RBAR(); MSTEP(0, 1); RBAR();
        /* k2 */ SBT(1, n0, 320);                      WAITVM(4); RBAR(); MSTEP(1, 0); RBAR();
        /* k3 */ SAT(0, zhi, 128); SBT(0, n0, 128);    WAITVM(6); RBAR(); MSTEP(1, 1); RBAR();
        /* k4 */ SBT(1, n0, 384);                      WAITVM(4); RBAR(); MSTEP(0, 0); RBAR();
        /* k5 */ SAT(1, zhi, 192); SBT(0, n0, 192);    WAITVM(6); RBAR(); MSTEP(0, 1); RBAR();
        /* k6 */ SBT(1, n0, 448);                      WAITVM(4); RBAR(); MSTEP(1, 0); RBAR();
        /* k7 */ SAT(0, zlo, 0);   SBT(0, n0, 0);      WAITVM(6); RBAR(); MSTEP(1, 1); RBAR();
        /* k8 */ SAT(1, zlo, 64);  SBT(1, n0, 64);     WAITVM(6); RBAR(); MSTEP(0, 0); RBAR();
        /* k9 */ SAT(0, zlo, 128); SBT(0, n0, 128);    WAITVM(6); RBAR(); MSTEP(1, 1); RBAR();
        /* k10*/ SAT(1, zlo, 192); SBT(1, n0, 192);    WAITVM(6); RBAR(); MSTEP(0, 0); RBAR();
        /* k11*/
        if (nc < 3) { SAT(0, zhi, 0); SBT(0, n0 + 256, 0); WAITVM(6); }
        else        { WAITVM(0); }
        RBAR(); MSTEP(1, 1); RBAR();

        // ---- register-local scan (overlaps with next nc's in-flight loads) ----
#pragma unroll
        for (int fr = 0; fr < 4; ++fr) {
            const int cbase = n0 + wcg * 64 + fr * 16 + lg * 4;
            const float4 e2v = *reinterpret_cast<const float4*>(&e2s[cbase]);
#pragma unroll
            for (int q = 0; q < 4; ++q) {
                const unsigned n = (unsigned)(cbase + q);
                const float e2q = (q == 0) ? e2v.x : (q == 1) ? e2v.y : (q == 2) ? e2v.z : e2v.w;
#pragma unroll
                for (int fc = 0; fc < 4; ++fc) {
                    float d = __fmaf_rn(-2.0f, acc[fr][fc][q], e2q);
                    bool lt1 = d < v1[fc];
                    bool lt2 = d < v2[fc];
                    bool lt3 = d < v3[fc];
                    v3[fc] = lt2 ? v2[fc] : (lt3 ? d : v3[fc]);
                    v2[fc] = lt1 ? v1[fc] : (lt2 ? d : v2[fc]);
                    pidx[fc] = lt1 ? ((pidx[fc] << 16) | n)
                                   : (lt2 ? ((pidx[fc] & 0xffffu) | (n << 16)) : pidx[fc]);
                    v1[fc] = lt1 ? d : v1[fc];
                }
            }
        }
    }

    // ---- ONE butterfly per slot across lg groups (masks 16, 32) ----
#pragma unroll
    for (int s = 0; s < 4; ++s) {
        float a1 = v1[s], a2 = v2[s], a3 = v3[s];
        int ai1 = (int)(pidx[s] & 0xffffu), ai2 = (int)(pidx[s] >> 16);
#pragma unroll
        for (int m = 16; m <= 32; m <<= 1) {
            float b1 = __shfl_xor(a1, m), b2 = __shfl_xor(a2, m), b3 = __shfl_xor(a3, m);
            int bi1 = __shfl_xor(ai1, m), bi2 = __shfl_xor(ai2, m);
            MERGE5(a1, ai1, a2, ai2, a3, b1, bi1, b2, bi2, b3);
        }
        if (lg == 0) {
            int row = wrg * 64 + s * 16 + lr;
            float* p = &mrg[(row * 4 + wcg) * 4];
            p[0] = a1; p[1] = a2; p[2] = a3;
            p[3] = __uint_as_float(((unsigned)ai1 & 0xffffu) | ((unsigned)ai2 << 16));
        }
    }
    __syncthreads();

    if (tid < 128) {
        const float* p0 = &mrg[(tid * 4 + 0) * 4];
        float A1 = p0[0], A2 = p0[1], A3 = p0[2];
        unsigned pk = __float_as_uint(p0[3]);
        int I1 = (int)(pk & 0xffffu), I2 = (int)(pk >> 16);
#pragma unroll
        for (int w = 1; w < 4; ++w) {
            const float* p = &mrg[(tid * 4 + w) * 4];
            float b1 = p[0], b2 = p[1], b3 = p[2];
            unsigned q = __float_as_uint(p[3]);
            int bi1 = (int)(q & 0xffffu), bi2 = (int)(q >> 16);
            MERGE5(A1, I1, A2, I2, A3, b1, bi1, b2, bi2, b3);
        }
        ci1[m0 + tid] = I1;
        ci2[m0 + tid] = I2;
        cflag[m0 + tid] = (A3 - A1 <= DELTA) ? 1 : 0;
    }
}

// ---------- exact fp32 distance (verified r3 chain) ----------
__device__ __forceinline__ float exact_g(const float* __restrict__ zr,
                                         const float* __restrict__ er,
                                         float z2v, float e2v) {
    float m = 0.f;
    for (int k = 0; k < 256; k += 4) {
        float4 zv = *reinterpret_cast<const float4*>(zr + k);
        float4 ev = *reinterpret_cast<const float4*>(er + k);
        m = __fmaf_rn(zv.x, ev.x, m);
        m = __fmaf_rn(zv.y, ev.y, m);
        m = __fmaf_rn(zv.z, ev.z, m);
        m = __fmaf_rn(zv.w, ev.w, m);
    }
    return __fsub_rn(__fadd_rn(z2v, e2v), __fmul_rn(2.0f, m));
}

// ---------- K3: exact top-2 refine + zq/loss; z staged ONCE in LDS ----------
__global__ __launch_bounds__(256)
void vq_refine_kernel(const float* __restrict__ z, const float* __restrict__ e,
                      const float* __restrict__ z2g, const float* __restrict__ e2f,
                      const int* __restrict__ ci1, const int* __restrict__ ci2,
                      const int* __restrict__ cflag,
                      float* __restrict__ out_idx, int* __restrict__ list,
                      int* __restrict__ counter,
                      float* __restrict__ out_zq, double* __restrict__ partials) {
    __shared__ __align__(16) float zl[64 * 256];   // 64 KiB
    __shared__ float  gbuf[128];
    __shared__ int    fIdx[64];
    __shared__ int    fFlag[64];
    __shared__ double dred[256];
    const int tid = threadIdx.x;
    const int r0  = blockIdx.x * 64;

    // stage 64 z-rows coalesced (float4): 4096 vec4 / 256 thr = 16 each
    {
        const float4* src = reinterpret_cast<const float4*>(z + (size_t)r0 * EDIM);
        float4* dst = reinterpret_cast<float4*>(zl);
#pragma unroll
        for (int i = 0; i < 16; ++i) dst[tid + 256 * i] = src[tid + 256 * i];
    }
    __syncthreads();

    if (tid < 128) {
        int r = tid >> 1, which = tid & 1;
        int row = r0 + r;
        int c = which ? ci2[row] : ci1[row];
        gbuf[tid] = exact_g(&zl[r * 256], e + (size_t)c * EDIM, z2g[row], e2f[c]);
    }
    __syncthreads();
    if (tid < 64) {
        int row = r0 + tid;
        int a = ci1[row], b = ci2[row];
        float ga = gbuf[tid * 2], gb = gbuf[tid * 2 + 1];
        int fi = (gb < ga || (gb == ga && b < a)) ? b : a;
        fIdx[tid] = fi;
        int fl = cflag[row];
        fFlag[tid] = fl;
        out_idx[row] = (float)fi;
        if (fl) { int p = atomicAdd(counter, 1); list[p] = row; }
    }
    __syncthreads();

    double lsum = 0.0;
    for (int r = 0; r < 64; ++r) {
        if (!fFlag[r]) {
            int row = r0 + r;
            float zv = zl[r * 256 + tid];
            float ev = e[(size_t)fIdx[r] * EDIM + tid];
            float dd = __fsub_rn(ev, zv);
            out_zq[(size_t)row * EDIM + tid] = __fadd_rn(zv, dd);
            lsum += (double)dd * (double)dd;
        }
    }
    dred[tid] = lsum;
    __syncthreads();
#pragma unroll
    for (int s = 128; s > 0; s >>= 1) {
        if (tid < s) dred[tid] += dred[tid + s];
        __syncthreads();
    }
    if (tid == 0) partials[blockIdx.x] = dred[0];
}

// ---------- K3b: full exact rescan for flagged rows ----------
__global__ __launch_bounds__(256)
void vq_fallback_kernel(const float* __restrict__ z, const float* __restrict__ e,
                        const float* __restrict__ z2g, const float* __restrict__ e2f,
                        const int* __restrict__ list, const int* __restrict__ counter,
                        float* __restrict__ out_idx, float* __restrict__ out_zq,
                        double* __restrict__ partials2) {
    __shared__ float  elds[64 * 257];
    __shared__ float  zlds[4][256];
    __shared__ float  z2s[4];
    __shared__ double dred[256];
    const int n   = *counter;
    const int tid = threadIdx.x;
    const int w   = tid >> 6;
    const int lane = tid & 63;
    double lsum = 0.0;

    for (int base = blockIdx.x * 4; base < n; base += gridDim.x * 4) {
        const int nr = min(4, n - base);
        __syncthreads();
        for (int i = tid; i < nr * 256; i += 256)
            zlds[i >> 8][i & 255] = z[(size_t)list[base + (i >> 8)] * EDIM + (i & 255)];
        if (tid < nr) z2s[tid] = z2g[list[base + tid]];

        float bv = FLT_MAX; int bi = 0x7fffffff;
        const int srow  = ((tid >> 4) & 3);
        const int scolq = (tid & 15) | ((tid >> 6) << 4);
        for (int c0 = 0; c0 < NE; c0 += 64) {
            __syncthreads();
#pragma unroll
            for (int s = 0; s < 16; ++s) {
                int row = 4 * s + srow;
                float4 v = *reinterpret_cast<const float4*>(e + (size_t)(c0 + row) * EDIM + scolq * 4);
                float* d = &elds[row * 257 + scolq * 4];
                d[0] = v.x; d[1] = v.y; d[2] = v.z; d[3] = v.w;
            }
            __syncthreads();
            const int code = c0 + lane;
            const float* er = &elds[lane * 257];
            const float* zr = zlds[w];
            float m = 0.f;
#pragma unroll 8
            for (int k = 0; k < 256; ++k)
                m = __fmaf_rn(zr[k], er[k], m);
            float g = __fsub_rn(__fadd_rn(z2s[w], e2f[code]), __fmul_rn(2.0f, m));
            if (g < bv || (g == bv && code < bi)) { bv = g; bi = code; }
        }
#pragma unroll
        for (int m2 = 1; m2 < 64; m2 <<= 1) {
            float ov = __shfl_xor(bv, m2); int oi = __shfl_xor(bi, m2);
            if (ov < bv || (ov == bv && oi < bi)) { bv = ov; bi = oi; }
        }
        if (w < nr) {
            int row = list[base + w];
            if (lane == 0) out_idx[row] = (float)bi;
            const float* er2 = e + (size_t)bi * EDIM;
            for (int c = lane; c < 256; c += 64) {
                float zv = zlds[w][c];
                float dd = __fsub_rn(er2[c], zv);
                out_zq[(size_t)row * EDIM + c] = __fadd_rn(zv, dd);
                lsum += (double)dd * (double)dd;
            }
        }
    }
    dred[tid] = lsum;
    __syncthreads();
#pragma unroll
    for (int s = 128; s > 0; s >>= 1) {
        if (tid < s) dred[tid] += dred[tid + s];
        __syncthreads();
    }
    if (tid == 0) partials2[blockIdx.x] = dred[0];
}

__global__ void vq_loss_kernel(const double* __restrict__ partials, int count,
                               float* __restrict__ out_loss) {
    __shared__ double s[256];
    const int tid = threadIdx.x;
    double v = 0.0;
    for (int i = tid; i < count; i += 256) v += partials[i];
    s[tid] = v;
    __syncthreads();
    for (int k = 128; k > 0; k >>= 1) {
        if (tid < k) s[tid] += s[tid + k];
        __syncthreads();
    }
    if (tid == 0) {
        double mean = s[0] / ((double)NROWS * (double)EDIM);
        out_loss[0] = (float)(1.25 * mean);
    }
}

// ================= fallback (proven r3 pipeline) if ws too small =================
__global__ __launch_bounds__(256, 2)
void vq_main_r3(const float* __restrict__ z, const float* __restrict__ e,
                const float* __restrict__ z2g, const float* __restrict__ e2g,
                float* __restrict__ out_zq, float* __restrict__ out_idx,
                double* __restrict__ partials) {
    __shared__ float A[BK][BM];
    __shared__ float Bm[BK][BN];
    __shared__ float e2s[BN];
    __shared__ int   fIdx[BM];
    __shared__ double dred[256];
    const int tid = threadIdx.x;
    const int m0 = blockIdx.x * BM;
    const int trow = tid >> 4, tcol = tid & 15;
    float z2r[8];
#pragma unroll
    for (int i = 0; i < 8; ++i) z2r[i] = z2g[m0 + trow * 8 + i];
    float bestV[8]; int bestI[8];
#pragma unroll
    for (int i = 0; i < 8; ++i) { bestV[i] = FLT_MAX; bestI[i] = 0; }
    for (int n0 = 0; n0 < NE; n0 += BN) {
        float acc[8][8];
#pragma unroll
        for (int i = 0; i < 8; ++i)
#pragma unroll
            for (int j = 0; j < 8; ++j) acc[i][j] = 0.f;
        __syncthreads();
        if (tid < BN) e2s[tid] = e2g[n0 + tid];
        for (int k0 = 0; k0 < EDIM; k0 += BK) {
            __syncthreads();
#pragma unroll
            for (int s = 0; s < 4; ++s) {
                int q = tid + 256 * s, row = q >> 3, kc = (q & 7) << 2;
                float4 va = *reinterpret_cast<const float4*>(z + (size_t)(m0 + row) * EDIM + k0 + kc);
                A[kc + 0][row] = va.x; A[kc + 1][row] = va.y; A[kc + 2][row] = va.z; A[kc + 3][row] = va.w;
                float4 vb = *reinterpret_cast<const float4*>(e + (size_t)(n0 + row) * EDIM + k0 + kc);
                Bm[kc + 0][row] = vb.x; Bm[kc + 1][row] = vb.y; Bm[kc + 2][row] = vb.z; Bm[kc + 3][row] = vb.w;
            }
            __syncthreads();
#pragma unroll
            for (int k = 0; k < BK; ++k) {
                float a[8], b[8];
                *reinterpret_cast<float4*>(&a[0]) = *reinterpret_cast<const float4*>(&A[k][trow * 8]);
                *reinterpret_cast<float4*>(&a[4]) = *reinterpret_cast<const float4*>(&A[k][trow * 8 + 4]);
                *reinterpret_cast<float4*>(&b[0]) = *reinterpret_cast<const float4*>(&Bm[k][tcol * 8]);
                *reinterpret_cast<float4*>(&b[4]) = *reinterpret_cast<const float4*>(&Bm[k][tcol * 8 + 4]);
#pragma unroll
                for (int i = 0; i < 8; ++i)
#pragma unroll
                    for (int j = 0; j < 8; ++j) acc[i][j] = __fmaf_rn(a[i], b[j], acc[i][j]);
            }
        }
#pragma unroll
        for (int i = 0; i < 8; ++i)
#pragma unroll
            for (int j = 0; j < 8; ++j) {
                int n = n0 + tcol * 8 + j;
                float d = __fsub_rn(__fadd_rn(z2r[i], e2s[tcol * 8 + j]), __fmul_rn(2.0f, acc[i][j]));
                if (d < bestV[i]) { bestV[i] = d; bestI[i] = n; }
            }
    }
    __syncthreads();
    float* red_v = &A[0][0];
    int* red_i = reinterpret_cast<int*>(&Bm[0][0]);
#pragma unroll
    for (int i = 0; i < 8; ++i) {
        int row = trow * 8 + i;
        red_v[row * 16 + tcol] = bestV[i];
        red_i[row * 16 + tcol] = bestI[i];
    }
    __syncthreads();
    if (tid < BM) {
        float b1 = FLT_MAX; int i1 = 0x7fffffff;
        for (int t = 0; t < 16; ++t) {
            float v = red_v[tid * 16 + t]; int id = red_i[tid * 16 + t];
            if (v < b1 || (v == b1 && id < i1)) { b1 = v; i1 = id; }
        }
        fIdx[tid] = i1;
        out_idx[m0 + tid] = (float)i1;
    }
    __syncthreads();
    double lsum = 0.0;
    for (int r = 0; r < BM; ++r) {
        int fi = fIdx[r];
        float zv = z[(size_t)(m0 + r) * EDIM + tid];
        float ev = e[(size_t)fi * EDIM + tid];
        float dd = __fsub_rn(ev, zv);
        out_zq[(size_t)(m0 + r) * EDIM + tid] = __fadd_rn(zv, dd);
        lsum += (double)dd * (double)dd;
    }
    dred[tid] = lsum;
    __syncthreads();
#pragma unroll
    for (int s = 128; s > 0; s >>= 1) {
        if (tid < s) dred[tid] += dred[tid + s];
        __syncthreads();
    }
    if (tid == 0) partials[blockIdx.x] = dred[0];
}

extern "C" void kernel_launch(void* const* d_in, const int* in_sizes, int n_in,
                              void* d_out, int out_size, void* d_ws, size_t ws_size,
                              hipStream_t stream) {
    (void)n_in; (void)out_size;
    const float* z = (const float*)d_in[0];
    const float* e = (const float*)d_in[1];
    if (in_sizes[0] == NE * EDIM) { const float* t = z; z = e; e = t; }
    float* out      = (float*)d_out;
    float* out_zq   = out;
    float* out_loss = out + (size_t)NROWS * EDIM;
    float* out_idx  = out_loss + 1;

    char* ws = (char*)d_ws;
    float*  z2g      = (float*)(ws + WS_Z2);
    float*  e2f      = (float*)(ws + WS_E2);
    double* partials = (double*)(ws + WS_PART);

    rownorm_kernel<<<(NE + 255) / 256, 256, 0, stream>>>(e, e2f, NE);

    if (ws_size >= WS_END) {
        int* cnt  = (int*)(ws + WS_CNT);
        int* list = (int*)(ws + WS_LIST);
        int* ci1  = (int*)(ws + WS_CI1);
        int* ci2  = (int*)(ws + WS_CI2);
        int* flg  = (int*)(ws + WS_FLG);
        u16* Bp   = (u16*)(ws + WS_BP);
        u16* zhi  = (u16*)d_out;                       // zq region as scratch
        u16* zlo  = zhi + (size_t)NROWS * EDIM;

        hipMemsetAsync(cnt, 0, 4, stream);
        rownorm_split_kernel<<<NROWS / 16, 256, 0, stream>>>(z, z2g, zhi, zlo);
        build_b_kernel<<<NE * EDIM / 256, 256, 0, stream>>>(e, Bp);
        vq_mfma_kernel<<<NROWS / 128, 512, 0, stream>>>(zhi, zlo, Bp, e2f, ci1, ci2, flg);
        vq_refine_kernel<<<NROWS / 64, 256, 0, stream>>>(z, e, z2g, e2f, ci1, ci2, flg,
                                                         out_idx, list, cnt, out_zq, partials);
        vq_fallback_kernel<<<512, 256, 0, stream>>>(z, e, z2g, e2f, list, cnt,
                                                    out_idx, out_zq, partials + 2048);
        vq_loss_kernel<<<1, 256, 0, stream>>>(partials, 2560, out_loss);
    } else {
        rownorm_kernel<<<NROWS / 256, 256, 0, stream>>>(z, z2g, NROWS);
        vq_main_r3<<<NROWS / BM, 256, 0, stream>>>(z, e, z2g, e2f, out_zq, out_idx, partials);
        vq_loss_kernel<<<1, 256, 0, stream>>>(partials, 1024, out_loss);
    }
}